// Round 1
// baseline (1186.264 us; speedup 1.0000x reference)
//
#include <hip/hip_runtime.h>
#include <hip/hip_bf16.h>
#include <math.h>

#define N_ITEMS 100001
#define DIM 128
#define NP 3
#define SEQ 100
#define NB 256
#define G3 384           // 3*DIM
#define TAU 0.1f
#define EPS_C 0.01f

// ---------------- ws layout (float offsets) ----------------
// g      : N*3      -> 300016 padded
// c      : N*3      -> 600032
// wxT    : 3*128*384 = 147456 -> 747488
// whT    : 147456   -> 894944
// hlast  : 256*384  = 98304 -> 993248
// gx     : 100*3*256*384 = 29491200 -> 30484448
#define OFF_G     0
#define OFF_C     300016
#define OFF_WXT   600032
#define OFF_WHT   747488
#define OFF_HLAST 894944
#define OFF_GX    993248
#define WS_FLOATS_PATHA (993248 + 29491200)

// ---------------- K1: transpose weights to [p][k][j] ----------------
__global__ void k_prep_w(const float* __restrict__ x2h, const float* __restrict__ h2h,
                         float* __restrict__ wxT, float* __restrict__ whT) {
    int idx = blockIdx.x * 256 + threadIdx.x;           // 3*128*384 = 147456
    if (idx >= NP * DIM * G3) return;
    int j = idx % G3;
    int k = (idx / G3) % DIM;
    int p = idx / (G3 * DIM);
    wxT[idx] = x2h[((size_t)p * G3 + j) * DIM + k];
    whT[idx] = h2h[((size_t)p * G3 + j) * DIM + k];
}

// ---------------- K2: per-item norm + softmax(g) + c = g/norm ----------------
__global__ __launch_bounds__(256) void k_gc(const float* __restrict__ emb,
                                            const float* __restrict__ pt,
                                            float* __restrict__ g, float* __restrict__ c) {
    __shared__ float pt_l[G3];
    __shared__ float ainv[NP];
    int tid = threadIdx.x;
    for (int u = tid; u < G3; u += 256) pt_l[u] = pt[u];
    __syncthreads();
    if (tid < NP) {
        float ss = 0.f;
        for (int k = 0; k < DIM; ++k) { float v = pt_l[tid * DIM + k]; ss += v * v; }
        ainv[tid] = 1.f / fmaxf(sqrtf(ss), 1e-12f);
    }
    __syncthreads();
    int lane = tid & 63, wv = tid >> 6;
    for (int it = 0; it < 8; ++it) {
        int i = blockIdx.x * 32 + wv * 8 + it;
        if (i >= N_ITEMS) continue;
        float a = emb[(size_t)i * DIM + lane];
        float b = emb[(size_t)i * DIM + 64 + lane];
        float ss = a * a + b * b;
        float d0 = a * pt_l[lane]       + b * pt_l[64 + lane];
        float d1 = a * pt_l[128 + lane] + b * pt_l[192 + lane];
        float d2 = a * pt_l[256 + lane] + b * pt_l[320 + lane];
        for (int off = 32; off > 0; off >>= 1) {
            ss += __shfl_down(ss, off);
            d0 += __shfl_down(d0, off);
            d1 += __shfl_down(d1, off);
            d2 += __shfl_down(d2, off);
        }
        if (lane == 0) {
            if (i == 0) {
                g[0] = 0.f; g[1] = 0.f; g[2] = 0.f;
                c[0] = 0.f; c[1] = 0.f; c[2] = 0.f;
            } else {
                float inv = 1.f / fmaxf(sqrtf(ss), 1e-12f);
                float l0 = d0 * ainv[0] * inv * (1.f / TAU);
                float l1 = d1 * ainv[1] * inv * (1.f / TAU);
                float l2 = d2 * ainv[2] * inv * (1.f / TAU);
                float m = fmaxf(l0, fmaxf(l1, l2));
                float e0 = expf(l0 - m), e1 = expf(l1 - m), e2 = expf(l2 - m);
                float is = 1.f / (e0 + e1 + e2);
                float g0 = e0 * is, g1 = e1 * is, g2 = e2 * is;
                g[(size_t)i * 3 + 0] = g0; g[(size_t)i * 3 + 1] = g1; g[(size_t)i * 3 + 2] = g2;
                c[(size_t)i * 3 + 0] = g0 * inv; c[(size_t)i * 3 + 1] = g1 * inv; c[(size_t)i * 3 + 2] = g2 * inv;
            }
        }
    }
}

// ---------------- K3 (path A): Gx[t][p][b][j] = dot_k(emb[seq[t,b]][k], Wx[p][j][k]) ----------------
__global__ __launch_bounds__(384) void k_gx(const int* __restrict__ seq,
                                            const float* __restrict__ emb,
                                            const float* __restrict__ wxT,
                                            float* __restrict__ gx) {
    int bid = blockIdx.x;               // 100*3*16 = 4800
    int bch = bid & 15;
    int p = (bid >> 4) % 3;
    int t = bid / 48;
    int b0 = bch * 16;
    __shared__ int idx_l[16];
    __shared__ __align__(16) float x_l[DIM * 16];  // [k][bc]
    int tid = threadIdx.x;
    if (tid < 16) idx_l[tid] = seq[t * NB + b0 + tid];
    __syncthreads();
    for (int u = tid; u < DIM * 16; u += 384) {
        int bc = u >> 7, k = u & 127;
        x_l[k * 16 + bc] = emb[(size_t)idx_l[bc] * DIM + k];
    }
    __syncthreads();
    int j = tid;
    float acc[16];
#pragma unroll
    for (int q = 0; q < 16; ++q) acc[q] = 0.f;
    const float* w = wxT + (size_t)p * (DIM * G3) + j;
#pragma unroll 2
    for (int k = 0; k < DIM; ++k) {
        float wv = w[(size_t)k * G3];
        const float4* xp = (const float4*)(x_l + k * 16);
        float4 x0 = xp[0], x1 = xp[1], x2 = xp[2], x3 = xp[3];
        acc[0]  += wv * x0.x; acc[1]  += wv * x0.y; acc[2]  += wv * x0.z; acc[3]  += wv * x0.w;
        acc[4]  += wv * x1.x; acc[5]  += wv * x1.y; acc[6]  += wv * x1.z; acc[7]  += wv * x1.w;
        acc[8]  += wv * x2.x; acc[9]  += wv * x2.y; acc[10] += wv * x2.z; acc[11] += wv * x2.w;
        acc[12] += wv * x3.x; acc[13] += wv * x3.y; acc[14] += wv * x3.z; acc[15] += wv * x3.w;
    }
    float* o = gx + ((size_t)(t * 3 + p) * NB + b0) * G3 + j;
#pragma unroll
    for (int bc = 0; bc < 16; ++bc) o[(size_t)bc * G3] = acc[bc];
}

// ---------------- K4: recurrence. Block = (p, 4 batch rows), all 100 steps ----------------
__global__ __launch_bounds__(384) void k_rnn(const int* __restrict__ seq,
                                             const int* __restrict__ lens,
                                             const float* __restrict__ emb,
                                             const float* __restrict__ g,
                                             const float* __restrict__ wxT,
                                             const float* __restrict__ whT,
                                             const float* __restrict__ gx, int useGx,
                                             float* __restrict__ hlast) {
    int bid = blockIdx.x;                // 192 = 3 * 64
    int b0 = (bid & 63) * 4;
    int p = bid >> 6;
    __shared__ __align__(16) float h_l[DIM * 4];    // [d][bc]
    __shared__ __align__(16) float x_l[DIM * 4];    // [k][bc]
    __shared__ __align__(16) float sx_l[G3 * 4];    // [j][bc]
    __shared__ __align__(16) float sh_l[G3 * 4];    // [j][bc]
    __shared__ float conc_l[4];
    __shared__ int idx_l[4];
    __shared__ int len_l[4];
    int tid = threadIdx.x;
    if (tid < 4) len_l[tid] = lens[b0 + tid];
    for (int u = tid; u < DIM * 4; u += 384) h_l[u] = 0.f;
    __syncthreads();
    const float* wh = whT + (size_t)p * (DIM * G3);
    const float* wx = wxT + (size_t)p * (DIM * G3);
    for (int t = 0; t < SEQ; ++t) {
        if (tid < 4) {
            int ix = seq[t * NB + b0 + tid];
            idx_l[tid] = ix;
            conc_l[tid] = g[(size_t)ix * 3 + p];
        }
        __syncthreads();
        if (!useGx) {
            for (int u = tid; u < DIM * 4; u += 384) {
                int bc = u >> 7, k = u & 127;
                x_l[k * 4 + bc] = emb[(size_t)idx_l[bc] * DIM + k];
            }
            __syncthreads();
        }
        int j = tid;
        float ax0, ax1, ax2, ax3;
        if (useGx) {
            const float* gp = gx + ((size_t)(t * 3 + p) * NB + b0) * G3 + j;
            ax0 = gp[0]; ax1 = gp[G3]; ax2 = gp[2 * G3]; ax3 = gp[3 * G3];
        } else {
            ax0 = ax1 = ax2 = ax3 = 0.f;
#pragma unroll 4
            for (int k = 0; k < DIM; ++k) {
                float wv = wx[(size_t)k * G3 + j];
                float4 xv = *(const float4*)(x_l + k * 4);
                ax0 += wv * xv.x; ax1 += wv * xv.y; ax2 += wv * xv.z; ax3 += wv * xv.w;
            }
        }
        float ah0 = 0.f, ah1 = 0.f, ah2 = 0.f, ah3 = 0.f;
#pragma unroll 4
        for (int k = 0; k < DIM; ++k) {
            float wv = wh[(size_t)k * G3 + j];
            float4 hv = *(const float4*)(h_l + k * 4);
            ah0 += wv * hv.x; ah1 += wv * hv.y; ah2 += wv * hv.z; ah3 += wv * hv.w;
        }
        *(float4*)(sx_l + j * 4) = make_float4(ax0, ax1, ax2, ax3);
        *(float4*)(sh_l + j * 4) = make_float4(ah0, ah1, ah2, ah3);
        __syncthreads();
        for (int u = tid; u < DIM * 4; u += 384) {
            int bc = u & 3, d = u >> 2;
            float sr = sx_l[d * 4 + bc] + sh_l[d * 4 + bc];
            float si = sx_l[(DIM + d) * 4 + bc] + sh_l[(DIM + d) * 4 + bc];
            float xn = sx_l[(2 * DIM + d) * 4 + bc];
            float hn = sh_l[(2 * DIM + d) * 4 + bc];
            float r  = 1.f / (1.f + expf(-sr));
            float ig = 1.f / (1.f + expf(-si));
            float ng = tanhf(xn + r * hn);
            float h  = h_l[d * 4 + bc];
            float cc = conc_l[bc];
            float multi = (cc >= EPS_C ? cc : 0.f) * ig;
            float hnew = h + multi * (ng - h);
            h_l[d * 4 + bc] = hnew;
            if (t == len_l[bc] - 1)
                hlast[(size_t)(b0 + bc) * G3 + p * DIM + d] = hnew;
        }
        __syncthreads();
    }
}

// ---------------- K5: logits GEMM (256 x 100001, K=384) + sigmoid ----------------
__global__ __launch_bounds__(256) void k_logits(const float* __restrict__ emb,
                                                const float* __restrict__ c,
                                                const float* __restrict__ hlast,
                                                float* __restrict__ out) {
    int ib = blockIdx.x;                // 782 * 2
    int it = ib >> 1;
    int bt = ib & 1;
    int i0 = it * 128;
    int b0 = bt * 128;
    __shared__ __align__(16) float A[32][132];   // [k][b]
    __shared__ __align__(16) float Bt[32][132];  // [k][i]
    int tid = threadIdx.x;
    int tx = tid & 15, ty = tid >> 4;
    float acc[8][8];
#pragma unroll
    for (int y = 0; y < 8; ++y)
#pragma unroll
        for (int x = 0; x < 8; ++x) acc[y][x] = 0.f;

    for (int kc = 0; kc < G3; kc += 32) {
        int p = kc >> 7;          // purpose for this chunk (32 | 128)
        int d0 = kc & 127;
        for (int u = tid; u < 4096; u += 256) {
            int k = u & 31, b = u >> 5;
            A[k][b] = hlast[(size_t)(b0 + b) * G3 + kc + k];
        }
        for (int u = tid; u < 4096; u += 256) {
            int dd = u & 31, i = u >> 5;
            int gi = i0 + i;
            float v = 0.f;
            if (gi < N_ITEMS) v = emb[(size_t)gi * DIM + d0 + dd] * c[(size_t)gi * 3 + p];
            Bt[dd][i] = v;
        }
        __syncthreads();
#pragma unroll 4
        for (int k = 0; k < 32; ++k) {
            float4 a0  = *(const float4*)&A[k][ty * 4];
            float4 a1  = *(const float4*)&A[k][ty * 4 + 64];
            float4 bb0 = *(const float4*)&Bt[k][tx * 4];
            float4 bb1 = *(const float4*)&Bt[k][tx * 4 + 64];
            float av[8] = {a0.x, a0.y, a0.z, a0.w, a1.x, a1.y, a1.z, a1.w};
            float bv[8] = {bb0.x, bb0.y, bb0.z, bb0.w, bb1.x, bb1.y, bb1.z, bb1.w};
#pragma unroll
            for (int y = 0; y < 8; ++y)
#pragma unroll
                for (int x = 0; x < 8; ++x) acc[y][x] += av[y] * bv[x];
        }
        __syncthreads();
    }
#pragma unroll
    for (int y = 0; y < 8; ++y) {
        int b = b0 + ty * 4 + (y & 3) + (y >> 2) * 64;
#pragma unroll
        for (int x = 0; x < 8; ++x) {
            int gi = i0 + tx * 4 + (x & 3) + (x >> 2) * 64;
            if (gi < N_ITEMS)
                out[(size_t)b * N_ITEMS + gi] = 1.f / (1.f + expf(-acc[y][x]));
        }
    }
}

extern "C" void kernel_launch(void* const* d_in, const int* in_sizes, int n_in,
                              void* d_out, int out_size, void* d_ws, size_t ws_size,
                              hipStream_t stream) {
    const int*   seq  = (const int*)d_in[0];
    const int*   lens = (const int*)d_in[1];
    const float* emb  = (const float*)d_in[2];
    const float* pt   = (const float*)d_in[3];
    const float* x2h  = (const float*)d_in[4];
    const float* h2h  = (const float*)d_in[5];
    float* out = (float*)d_out;
    float* ws  = (float*)d_ws;

    float* g     = ws + OFF_G;
    float* c     = ws + OFF_C;
    float* wxT   = ws + OFF_WXT;
    float* whT   = ws + OFF_WHT;
    float* hlast = ws + OFF_HLAST;
    float* gxbuf = ws + OFF_GX;

    int useGx = (ws_size >= (size_t)WS_FLOATS_PATHA * 4) ? 1 : 0;

    k_prep_w<<<576, 256, 0, stream>>>(x2h, h2h, wxT, whT);
    k_gc<<<3126, 256, 0, stream>>>(emb, pt, g, c);
    if (useGx) k_gx<<<4800, 384, 0, stream>>>(seq, emb, wxT, gxbuf);
    k_rnn<<<192, 384, 0, stream>>>(seq, lens, emb, g, wxT, whT, gxbuf, useGx, hlast);
    k_logits<<<1564, 256, 0, stream>>>(emb, c, hlast, out);
}

// Round 2
// 788.905 us; speedup vs baseline: 1.5037x; 1.5037x over previous
//
#include <hip/hip_runtime.h>
#include <hip/hip_bf16.h>
#include <math.h>

#define N_ITEMS 100001
#define DIM 128
#define NP 3
#define SEQ 100
#define NB 256
#define G3 384           // 3*DIM
#define TAU 0.1f
#define EPS_C 0.01f

// ---------------- ws layout (float offsets) ----------------
#define OFF_G     0
#define OFF_C     300016
#define OFF_WXT   600032
#define OFF_WHT   747488
#define OFF_HLAST 894944
#define OFF_GX    993248
#define WS_FLOATS_PATHA (993248 + 29491200)

__device__ __forceinline__ float sigmoidf_fast(float x) {
    return __builtin_amdgcn_rcpf(1.f + __builtin_amdgcn_exp2f(-1.4426950408889634f * x));
}
__device__ __forceinline__ float tanhf_fast(float x) {
    // tanh(x) = 1 - 2/(exp(2x)+1);  exp(2x) = 2^(2x*log2(e))
    return 1.f - 2.f * __builtin_amdgcn_rcpf(1.f + __builtin_amdgcn_exp2f(2.8853900817779268f * x));
}

// ---------------- K1: transpose weights to [p][k][j] ----------------
__global__ void k_prep_w(const float* __restrict__ x2h, const float* __restrict__ h2h,
                         float* __restrict__ wxT, float* __restrict__ whT) {
    int idx = blockIdx.x * 256 + threadIdx.x;           // 3*128*384 = 147456
    if (idx >= NP * DIM * G3) return;
    int j = idx % G3;
    int k = (idx / G3) % DIM;
    int p = idx / (G3 * DIM);
    wxT[idx] = x2h[((size_t)p * G3 + j) * DIM + k];
    whT[idx] = h2h[((size_t)p * G3 + j) * DIM + k];
}

// ---------------- K2: per-item norm + softmax(g) + c = g/norm ----------------
__global__ __launch_bounds__(256) void k_gc(const float* __restrict__ emb,
                                            const float* __restrict__ pt,
                                            float* __restrict__ g, float* __restrict__ c) {
    __shared__ float pt_l[G3];
    __shared__ float ainv[NP];
    int tid = threadIdx.x;
    for (int u = tid; u < G3; u += 256) pt_l[u] = pt[u];
    __syncthreads();
    if (tid < NP) {
        float ss = 0.f;
        for (int k = 0; k < DIM; ++k) { float v = pt_l[tid * DIM + k]; ss += v * v; }
        ainv[tid] = 1.f / fmaxf(sqrtf(ss), 1e-12f);
    }
    __syncthreads();
    int lane = tid & 63, wv = tid >> 6;
    for (int it = 0; it < 8; ++it) {
        int i = blockIdx.x * 32 + wv * 8 + it;
        if (i >= N_ITEMS) continue;
        float a = emb[(size_t)i * DIM + lane];
        float b = emb[(size_t)i * DIM + 64 + lane];
        float ss = a * a + b * b;
        float d0 = a * pt_l[lane]       + b * pt_l[64 + lane];
        float d1 = a * pt_l[128 + lane] + b * pt_l[192 + lane];
        float d2 = a * pt_l[256 + lane] + b * pt_l[320 + lane];
        for (int off = 32; off > 0; off >>= 1) {
            ss += __shfl_down(ss, off);
            d0 += __shfl_down(d0, off);
            d1 += __shfl_down(d1, off);
            d2 += __shfl_down(d2, off);
        }
        if (lane == 0) {
            if (i == 0) {
                g[0] = 0.f; g[1] = 0.f; g[2] = 0.f;
                c[0] = 0.f; c[1] = 0.f; c[2] = 0.f;
            } else {
                float inv = 1.f / fmaxf(sqrtf(ss), 1e-12f);
                float l0 = d0 * ainv[0] * inv * (1.f / TAU);
                float l1 = d1 * ainv[1] * inv * (1.f / TAU);
                float l2 = d2 * ainv[2] * inv * (1.f / TAU);
                float m = fmaxf(l0, fmaxf(l1, l2));
                float e0 = expf(l0 - m), e1 = expf(l1 - m), e2 = expf(l2 - m);
                float is = 1.f / (e0 + e1 + e2);
                float g0 = e0 * is, g1 = e1 * is, g2 = e2 * is;
                g[(size_t)i * 3 + 0] = g0; g[(size_t)i * 3 + 1] = g1; g[(size_t)i * 3 + 2] = g2;
                c[(size_t)i * 3 + 0] = g0 * inv; c[(size_t)i * 3 + 1] = g1 * inv; c[(size_t)i * 3 + 2] = g2 * inv;
            }
        }
    }
}

// ---------------- K3 (path A): Gx[t][p][b][j] ----------------
__global__ __launch_bounds__(384) void k_gx(const int* __restrict__ seq,
                                            const float* __restrict__ emb,
                                            const float* __restrict__ wxT,
                                            float* __restrict__ gx) {
    int bid = blockIdx.x;               // 100*3*16 = 4800
    int bch = bid & 15;
    int p = (bid >> 4) % 3;
    int t = bid / 48;
    int b0 = bch * 16;
    __shared__ int idx_l[16];
    __shared__ __align__(16) float x_l[DIM * 16];  // [k][bc]
    int tid = threadIdx.x;
    if (tid < 16) idx_l[tid] = seq[t * NB + b0 + tid];
    __syncthreads();
    for (int u = tid; u < DIM * 16; u += 384) {
        int bc = u >> 7, k = u & 127;
        x_l[k * 16 + bc] = emb[(size_t)idx_l[bc] * DIM + k];
    }
    __syncthreads();
    int j = tid;
    float acc[16];
#pragma unroll
    for (int q = 0; q < 16; ++q) acc[q] = 0.f;
    const float* w = wxT + (size_t)p * (DIM * G3) + j;
#pragma unroll 2
    for (int k = 0; k < DIM; ++k) {
        float wv = w[(size_t)k * G3];
        const float4* xp = (const float4*)(x_l + k * 16);
        float4 x0 = xp[0], x1 = xp[1], x2 = xp[2], x3 = xp[3];
        acc[0]  += wv * x0.x; acc[1]  += wv * x0.y; acc[2]  += wv * x0.z; acc[3]  += wv * x0.w;
        acc[4]  += wv * x1.x; acc[5]  += wv * x1.y; acc[6]  += wv * x1.z; acc[7]  += wv * x1.w;
        acc[8]  += wv * x2.x; acc[9]  += wv * x2.y; acc[10] += wv * x2.z; acc[11] += wv * x2.w;
        acc[12] += wv * x3.x; acc[13] += wv * x3.y; acc[14] += wv * x3.z; acc[15] += wv * x3.w;
    }
    float* o = gx + ((size_t)(t * 3 + p) * NB + b0) * G3 + j;
#pragma unroll
    for (int bc = 0; bc < 16; ++bc) o[(size_t)bc * G3] = acc[bc];
}

// ---------------- K4 v2: recurrence, Wh held in VGPRs ----------------
// grid: 192 = 3p * 64 batch-groups(4).  block: 512 = 4 kg * 128 jg.
// thread (kg,jg) owns Wh[p][kg*32 .. +31][jg*3 .. +2] in registers (96 VGPRs).
__global__ __launch_bounds__(512, 2) void k_rnn2(const int* __restrict__ seq,
                                                 const int* __restrict__ lens,
                                                 const float* __restrict__ g,
                                                 const float* __restrict__ whT,
                                                 const float* __restrict__ gx,
                                                 float* __restrict__ hlast) {
    int bid = blockIdx.x;
    int b0 = (bid & 63) * 4;
    int p  = bid >> 6;
    int tid = threadIdx.x;
    int kg = tid >> 7;        // 0..3 (k block of 32)
    int jg = tid & 127;       // 0..127 (3 cols each)

    __shared__ __align__(16) float h_l[DIM * 4];       // [d][b]
    __shared__ float part_l[4][4][388];                // [b][kg][j] (pad 388)
    __shared__ float conc_l[4];
    __shared__ int len_l[4];

    // one-time: weights into registers
    float w[32][3];
    const float* wp = whT + (size_t)p * (DIM * G3) + (size_t)(kg * 32) * G3 + jg * 3;
#pragma unroll
    for (int kk = 0; kk < 32; ++kk) {
        w[kk][0] = wp[0]; w[kk][1] = wp[1]; w[kk][2] = wp[2];
        wp += G3;
    }
    if (tid < 4) len_l[tid] = lens[b0 + tid];
    for (int u = tid; u < DIM * 4; u += 512) h_l[u] = 0.f;
    __syncthreads();

    int gb = tid >> 7;        // gate phase: batch
    int gd = tid & 127;       // gate phase: dim

    for (int t = 0; t < SEQ; ++t) {
        if (tid < 4) {
            int ix = seq[t * NB + b0 + tid];
            conc_l[tid] = g[(size_t)ix * 3 + p];
        }
        // prefetch gx for this step (hidden under FMA phase; L3-resident)
        const float* gp = gx + ((size_t)(t * 3 + p) * NB + (b0 + gb)) * G3 + gd;
        float gxr = gp[0], gxi = gp[DIM], gxn = gp[2 * DIM];

        // gh partial GEMM: 32 iters of broadcast-read + 12 FMA
        float a0x = 0.f, a0y = 0.f, a0z = 0.f, a0w = 0.f;
        float a1x = 0.f, a1y = 0.f, a1z = 0.f, a1w = 0.f;
        float a2x = 0.f, a2y = 0.f, a2z = 0.f, a2w = 0.f;
        const float* hl = h_l + kg * 32 * 4;
#pragma unroll
        for (int kk = 0; kk < 32; ++kk) {
            float4 hv = *(const float4*)(hl + kk * 4);
            a0x += w[kk][0] * hv.x; a0y += w[kk][0] * hv.y; a0z += w[kk][0] * hv.z; a0w += w[kk][0] * hv.w;
            a1x += w[kk][1] * hv.x; a1y += w[kk][1] * hv.y; a1z += w[kk][1] * hv.z; a1w += w[kk][1] * hv.w;
            a2x += w[kk][2] * hv.x; a2y += w[kk][2] * hv.y; a2z += w[kk][2] * hv.z; a2w += w[kk][2] * hv.w;
        }
        int j0 = jg * 3;
        part_l[0][kg][j0] = a0x; part_l[1][kg][j0] = a0y; part_l[2][kg][j0] = a0z; part_l[3][kg][j0] = a0w;
        part_l[0][kg][j0+1] = a1x; part_l[1][kg][j0+1] = a1y; part_l[2][kg][j0+1] = a1z; part_l[3][kg][j0+1] = a1w;
        part_l[0][kg][j0+2] = a2x; part_l[1][kg][j0+2] = a2y; part_l[2][kg][j0+2] = a2z; part_l[3][kg][j0+2] = a2w;
        __syncthreads();

        // gate phase: one (b,d) per thread
        float ghr = part_l[gb][0][gd]         + part_l[gb][1][gd]         + part_l[gb][2][gd]         + part_l[gb][3][gd];
        float ghi = part_l[gb][0][DIM+gd]     + part_l[gb][1][DIM+gd]     + part_l[gb][2][DIM+gd]     + part_l[gb][3][DIM+gd];
        float ghn = part_l[gb][0][2*DIM+gd]   + part_l[gb][1][2*DIM+gd]   + part_l[gb][2][2*DIM+gd]   + part_l[gb][3][2*DIM+gd];
        float r  = sigmoidf_fast(gxr + ghr);
        float ig = sigmoidf_fast(gxi + ghi);
        float ng = tanhf_fast(gxn + r * ghn);
        float h  = h_l[gd * 4 + gb];
        float cc = conc_l[gb];
        float multi = (cc >= EPS_C ? cc : 0.f) * ig;
        float hnew = h + multi * (ng - h);
        h_l[gd * 4 + gb] = hnew;
        if (t == len_l[gb] - 1)
            hlast[(size_t)(b0 + gb) * G3 + p * DIM + gd] = hnew;
        __syncthreads();
    }
}

// ---------------- K4 fallback (no gx buffer): original version ----------------
__global__ __launch_bounds__(384) void k_rnn(const int* __restrict__ seq,
                                             const int* __restrict__ lens,
                                             const float* __restrict__ emb,
                                             const float* __restrict__ g,
                                             const float* __restrict__ wxT,
                                             const float* __restrict__ whT,
                                             float* __restrict__ hlast) {
    int bid = blockIdx.x;
    int b0 = (bid & 63) * 4;
    int p = bid >> 6;
    __shared__ __align__(16) float h_l[DIM * 4];
    __shared__ __align__(16) float x_l[DIM * 4];
    __shared__ __align__(16) float sx_l[G3 * 4];
    __shared__ __align__(16) float sh_l[G3 * 4];
    __shared__ float conc_l[4];
    __shared__ int idx_l[4];
    __shared__ int len_l[4];
    int tid = threadIdx.x;
    if (tid < 4) len_l[tid] = lens[b0 + tid];
    for (int u = tid; u < DIM * 4; u += 384) h_l[u] = 0.f;
    __syncthreads();
    const float* wh = whT + (size_t)p * (DIM * G3);
    const float* wx = wxT + (size_t)p * (DIM * G3);
    for (int t = 0; t < SEQ; ++t) {
        if (tid < 4) {
            int ix = seq[t * NB + b0 + tid];
            idx_l[tid] = ix;
            conc_l[tid] = g[(size_t)ix * 3 + p];
        }
        __syncthreads();
        for (int u = tid; u < DIM * 4; u += 384) {
            int bc = u >> 7, k = u & 127;
            x_l[k * 4 + bc] = emb[(size_t)idx_l[bc] * DIM + k];
        }
        __syncthreads();
        int j = tid;
        float ax0 = 0.f, ax1 = 0.f, ax2 = 0.f, ax3 = 0.f;
#pragma unroll 4
        for (int k = 0; k < DIM; ++k) {
            float wv = wx[(size_t)k * G3 + j];
            float4 xv = *(const float4*)(x_l + k * 4);
            ax0 += wv * xv.x; ax1 += wv * xv.y; ax2 += wv * xv.z; ax3 += wv * xv.w;
        }
        float ah0 = 0.f, ah1 = 0.f, ah2 = 0.f, ah3 = 0.f;
#pragma unroll 4
        for (int k = 0; k < DIM; ++k) {
            float wv = wh[(size_t)k * G3 + j];
            float4 hv = *(const float4*)(h_l + k * 4);
            ah0 += wv * hv.x; ah1 += wv * hv.y; ah2 += wv * hv.z; ah3 += wv * hv.w;
        }
        *(float4*)(sx_l + j * 4) = make_float4(ax0, ax1, ax2, ax3);
        *(float4*)(sh_l + j * 4) = make_float4(ah0, ah1, ah2, ah3);
        __syncthreads();
        for (int u = tid; u < DIM * 4; u += 384) {
            int bc = u & 3, d = u >> 2;
            float sr = sx_l[d * 4 + bc] + sh_l[d * 4 + bc];
            float si = sx_l[(DIM + d) * 4 + bc] + sh_l[(DIM + d) * 4 + bc];
            float xn = sx_l[(2 * DIM + d) * 4 + bc];
            float hn = sh_l[(2 * DIM + d) * 4 + bc];
            float r  = sigmoidf_fast(sr);
            float ig = sigmoidf_fast(si);
            float ng = tanhf_fast(xn + r * hn);
            float h  = h_l[d * 4 + bc];
            float cc = conc_l[bc];
            float multi = (cc >= EPS_C ? cc : 0.f) * ig;
            float hnew = h + multi * (ng - h);
            h_l[d * 4 + bc] = hnew;
            if (t == len_l[bc] - 1)
                hlast[(size_t)(b0 + bc) * G3 + p * DIM + d] = hnew;
        }
        __syncthreads();
    }
}

// ---------------- K5: logits GEMM (256 x 100001, K=384) + sigmoid ----------------
__global__ __launch_bounds__(256) void k_logits(const float* __restrict__ emb,
                                                const float* __restrict__ c,
                                                const float* __restrict__ hlast,
                                                float* __restrict__ out) {
    int ib = blockIdx.x;
    int it = ib >> 1;
    int bt = ib & 1;
    int i0 = it * 128;
    int b0 = bt * 128;
    __shared__ __align__(16) float A[32][132];
    __shared__ __align__(16) float Bt[32][132];
    int tid = threadIdx.x;
    int tx = tid & 15, ty = tid >> 4;
    float acc[8][8];
#pragma unroll
    for (int y = 0; y < 8; ++y)
#pragma unroll
        for (int x = 0; x < 8; ++x) acc[y][x] = 0.f;

    for (int kc = 0; kc < G3; kc += 32) {
        int p = kc >> 7;
        int d0 = kc & 127;
        for (int u = tid; u < 4096; u += 256) {
            int k = u & 31, b = u >> 5;
            A[k][b] = hlast[(size_t)(b0 + b) * G3 + kc + k];
        }
        for (int u = tid; u < 4096; u += 256) {
            int dd = u & 31, i = u >> 5;
            int gi = i0 + i;
            float v = 0.f;
            if (gi < N_ITEMS) v = emb[(size_t)gi * DIM + d0 + dd] * c[(size_t)gi * 3 + p];
            Bt[dd][i] = v;
        }
        __syncthreads();
#pragma unroll 4
        for (int k = 0; k < 32; ++k) {
            float4 a0  = *(const float4*)&A[k][ty * 4];
            float4 a1  = *(const float4*)&A[k][ty * 4 + 64];
            float4 bb0 = *(const float4*)&Bt[k][tx * 4];
            float4 bb1 = *(const float4*)&Bt[k][tx * 4 + 64];
            float av[8] = {a0.x, a0.y, a0.z, a0.w, a1.x, a1.y, a1.z, a1.w};
            float bv[8] = {bb0.x, bb0.y, bb0.z, bb0.w, bb1.x, bb1.y, bb1.z, bb1.w};
#pragma unroll
            for (int y = 0; y < 8; ++y)
#pragma unroll
                for (int x = 0; x < 8; ++x) acc[y][x] += av[y] * bv[x];
        }
        __syncthreads();
    }
#pragma unroll
    for (int y = 0; y < 8; ++y) {
        int b = b0 + ty * 4 + (y & 3) + (y >> 2) * 64;
#pragma unroll
        for (int x = 0; x < 8; ++x) {
            int gi = i0 + tx * 4 + (x & 3) + (x >> 2) * 64;
            if (gi < N_ITEMS)
                out[(size_t)b * N_ITEMS + gi] = 1.f / (1.f + expf(-acc[y][x]));
        }
    }
}

extern "C" void kernel_launch(void* const* d_in, const int* in_sizes, int n_in,
                              void* d_out, int out_size, void* d_ws, size_t ws_size,
                              hipStream_t stream) {
    const int*   seq  = (const int*)d_in[0];
    const int*   lens = (const int*)d_in[1];
    const float* emb  = (const float*)d_in[2];
    const float* pt   = (const float*)d_in[3];
    const float* x2h  = (const float*)d_in[4];
    const float* h2h  = (const float*)d_in[5];
    float* out = (float*)d_out;
    float* ws  = (float*)d_ws;

    float* g     = ws + OFF_G;
    float* c     = ws + OFF_C;
    float* wxT   = ws + OFF_WXT;
    float* whT   = ws + OFF_WHT;
    float* hlast = ws + OFF_HLAST;
    float* gxbuf = ws + OFF_GX;

    int useGx = (ws_size >= (size_t)WS_FLOATS_PATHA * 4) ? 1 : 0;

    k_prep_w<<<576, 256, 0, stream>>>(x2h, h2h, wxT, whT);
    k_gc<<<3126, 256, 0, stream>>>(emb, pt, g, c);
    if (useGx) {
        k_gx<<<4800, 384, 0, stream>>>(seq, emb, wxT, gxbuf);
        k_rnn2<<<192, 512, 0, stream>>>(seq, lens, g, whT, gxbuf, hlast);
    } else {
        k_rnn<<<192, 384, 0, stream>>>(seq, lens, emb, g, wxT, whT, hlast);
    }
    k_logits<<<1564, 256, 0, stream>>>(emb, c, hlast, out);
}

// Round 3
// 652.205 us; speedup vs baseline: 1.8189x; 1.2096x over previous
//
#include <hip/hip_runtime.h>
#include <hip/hip_bf16.h>
#include <math.h>

#define N_ITEMS 100001
#define DIM 128
#define NP 3
#define SEQ 100
#define NB 256
#define G3 384           // 3*DIM
#define TAU 0.1f
#define EPS_C 0.01f

// ---------------- ws layout (float offsets) ----------------
#define OFF_G     0
#define OFF_C     300016
#define OFF_WXT   600032
#define OFF_WHT   747488
#define OFF_HLAST 894944
#define OFF_GX    993248
// hl_hi / hl_lo (bf16-packed hlast fragments) alias the gx region: gx is dead
// after k_rnn2, hl is produced after it. 98304 shorts each.
#define WS_FLOATS_PATHA (993248 + 29491200)

typedef float f32x4 __attribute__((ext_vector_type(4)));
typedef short s16x8 __attribute__((ext_vector_type(8)));

__device__ __forceinline__ float sigmoidf_fast(float x) {
    return __builtin_amdgcn_rcpf(1.f + __builtin_amdgcn_exp2f(-1.4426950408889634f * x));
}
__device__ __forceinline__ float tanhf_fast(float x) {
    return 1.f - 2.f * __builtin_amdgcn_rcpf(1.f + __builtin_amdgcn_exp2f(2.8853900817779268f * x));
}
// fp32 -> bf16 round-to-nearest-even (bit trick)
__device__ __forceinline__ unsigned short f2bf(float x) {
    union { float f; unsigned u; } v; v.f = x;
    unsigned r = v.u + 0x7fffu + ((v.u >> 16) & 1u);
    return (unsigned short)(r >> 16);
}
__device__ __forceinline__ float bf2f(unsigned short h) {
    union { unsigned u; float f; } v; v.u = ((unsigned)h) << 16;
    return v.f;
}

// ---------------- K1: transpose weights to [p][k][j] ----------------
__global__ void k_prep_w(const float* __restrict__ x2h, const float* __restrict__ h2h,
                         float* __restrict__ wxT, float* __restrict__ whT) {
    int idx = blockIdx.x * 256 + threadIdx.x;
    if (idx >= NP * DIM * G3) return;
    int j = idx % G3;
    int k = (idx / G3) % DIM;
    int p = idx / (G3 * DIM);
    wxT[idx] = x2h[((size_t)p * G3 + j) * DIM + k];
    whT[idx] = h2h[((size_t)p * G3 + j) * DIM + k];
}

// ---------------- K2: per-item norm + softmax(g) + c = g/norm ----------------
__global__ __launch_bounds__(256) void k_gc(const float* __restrict__ emb,
                                            const float* __restrict__ pt,
                                            float* __restrict__ g, float* __restrict__ c) {
    __shared__ float pt_l[G3];
    __shared__ float ainv[NP];
    int tid = threadIdx.x;
    for (int u = tid; u < G3; u += 256) pt_l[u] = pt[u];
    __syncthreads();
    if (tid < NP) {
        float ss = 0.f;
        for (int k = 0; k < DIM; ++k) { float v = pt_l[tid * DIM + k]; ss += v * v; }
        ainv[tid] = 1.f / fmaxf(sqrtf(ss), 1e-12f);
    }
    __syncthreads();
    int lane = tid & 63, wv = tid >> 6;
    for (int it = 0; it < 8; ++it) {
        int i = blockIdx.x * 32 + wv * 8 + it;
        if (i >= N_ITEMS) continue;
        float a = emb[(size_t)i * DIM + lane];
        float b = emb[(size_t)i * DIM + 64 + lane];
        float ss = a * a + b * b;
        float d0 = a * pt_l[lane]       + b * pt_l[64 + lane];
        float d1 = a * pt_l[128 + lane] + b * pt_l[192 + lane];
        float d2 = a * pt_l[256 + lane] + b * pt_l[320 + lane];
        for (int off = 32; off > 0; off >>= 1) {
            ss += __shfl_down(ss, off);
            d0 += __shfl_down(d0, off);
            d1 += __shfl_down(d1, off);
            d2 += __shfl_down(d2, off);
        }
        if (lane == 0) {
            if (i == 0) {
                g[0] = 0.f; g[1] = 0.f; g[2] = 0.f;
                c[0] = 0.f; c[1] = 0.f; c[2] = 0.f;
            } else {
                float inv = 1.f / fmaxf(sqrtf(ss), 1e-12f);
                float l0 = d0 * ainv[0] * inv * (1.f / TAU);
                float l1 = d1 * ainv[1] * inv * (1.f / TAU);
                float l2 = d2 * ainv[2] * inv * (1.f / TAU);
                float m = fmaxf(l0, fmaxf(l1, l2));
                float e0 = expf(l0 - m), e1 = expf(l1 - m), e2 = expf(l2 - m);
                float is = 1.f / (e0 + e1 + e2);
                float g0 = e0 * is, g1 = e1 * is, g2 = e2 * is;
                g[(size_t)i * 3 + 0] = g0; g[(size_t)i * 3 + 1] = g1; g[(size_t)i * 3 + 2] = g2;
                c[(size_t)i * 3 + 0] = g0 * inv; c[(size_t)i * 3 + 1] = g1 * inv; c[(size_t)i * 3 + 2] = g2 * inv;
            }
        }
    }
}

// ---------------- K3 (path A): Gx[t][p][b][j] ----------------
__global__ __launch_bounds__(384) void k_gx(const int* __restrict__ seq,
                                            const float* __restrict__ emb,
                                            const float* __restrict__ wxT,
                                            float* __restrict__ gx) {
    int bid = blockIdx.x;               // 100*3*16 = 4800
    int bch = bid & 15;
    int p = (bid >> 4) % 3;
    int t = bid / 48;
    int b0 = bch * 16;
    __shared__ int idx_l[16];
    __shared__ __align__(16) float x_l[DIM * 16];
    int tid = threadIdx.x;
    if (tid < 16) idx_l[tid] = seq[t * NB + b0 + tid];
    __syncthreads();
    for (int u = tid; u < DIM * 16; u += 384) {
        int bc = u >> 7, k = u & 127;
        x_l[k * 16 + bc] = emb[(size_t)idx_l[bc] * DIM + k];
    }
    __syncthreads();
    int j = tid;
    float acc[16];
#pragma unroll
    for (int q = 0; q < 16; ++q) acc[q] = 0.f;
    const float* w = wxT + (size_t)p * (DIM * G3) + j;
#pragma unroll 2
    for (int k = 0; k < DIM; ++k) {
        float wv = w[(size_t)k * G3];
        const float4* xp = (const float4*)(x_l + k * 16);
        float4 x0 = xp[0], x1 = xp[1], x2 = xp[2], x3 = xp[3];
        acc[0]  += wv * x0.x; acc[1]  += wv * x0.y; acc[2]  += wv * x0.z; acc[3]  += wv * x0.w;
        acc[4]  += wv * x1.x; acc[5]  += wv * x1.y; acc[6]  += wv * x1.z; acc[7]  += wv * x1.w;
        acc[8]  += wv * x2.x; acc[9]  += wv * x2.y; acc[10] += wv * x2.z; acc[11] += wv * x2.w;
        acc[12] += wv * x3.x; acc[13] += wv * x3.y; acc[14] += wv * x3.z; acc[15] += wv * x3.w;
    }
    float* o = gx + ((size_t)(t * 3 + p) * NB + b0) * G3 + j;
#pragma unroll
    for (int bc = 0; bc < 16; ++bc) o[(size_t)bc * G3] = acc[bc];
}

// ---------------- K4 v2: recurrence, Wh in VGPRs, b-group = 2 ----------------
// grid: 384 = 3p * 128 groups(2b).  block: 512 = 4 kg * 128 jg.
__global__ __launch_bounds__(512, 2) void k_rnn2(const int* __restrict__ seq,
                                                 const int* __restrict__ lens,
                                                 const float* __restrict__ g,
                                                 const float* __restrict__ whT,
                                                 const float* __restrict__ gx,
                                                 float* __restrict__ hlast) {
    int bid = blockIdx.x;
    int b0 = (bid & 127) * 2;
    int p  = bid >> 7;
    int tid = threadIdx.x;
    int kg = tid >> 7;        // 0..3
    int jg = tid & 127;       // 0..127, 3 cols each

    __shared__ __align__(16) float h_l[DIM * 2];       // [d][b]
    __shared__ float part_l[2][4][388];
    __shared__ float conc_l[2];
    __shared__ int len_l[2];

    float w[32][3];
    const float* wp = whT + (size_t)p * (DIM * G3) + (size_t)(kg * 32) * G3 + jg * 3;
#pragma unroll
    for (int kk = 0; kk < 32; ++kk) {
        w[kk][0] = wp[0]; w[kk][1] = wp[1]; w[kk][2] = wp[2];
        wp += G3;
    }
    if (tid < 2) len_l[tid] = lens[b0 + tid];
    for (int u = tid; u < DIM * 2; u += 512) h_l[u] = 0.f;
    __syncthreads();

    int gb = tid >> 7;        // 0..3 (only 0..1 active in gate phase)
    int gd = tid & 127;
    int gbb = gb & 1;

    for (int t = 0; t < SEQ; ++t) {
        if (tid < 2) {
            int ix = seq[t * NB + b0 + tid];
            conc_l[tid] = g[(size_t)ix * 3 + p];
        }
        const float* gp = gx + ((size_t)(t * 3 + p) * NB + (b0 + gbb)) * G3 + gd;
        float gxr = gp[0], gxi = gp[DIM], gxn = gp[2 * DIM];

        float a0x = 0.f, a0y = 0.f;
        float a1x = 0.f, a1y = 0.f;
        float a2x = 0.f, a2y = 0.f;
        const float* hl = h_l + kg * 32 * 2;
#pragma unroll
        for (int kk = 0; kk < 32; ++kk) {
            float2 hv = *(const float2*)(hl + kk * 2);
            a0x += w[kk][0] * hv.x; a0y += w[kk][0] * hv.y;
            a1x += w[kk][1] * hv.x; a1y += w[kk][1] * hv.y;
            a2x += w[kk][2] * hv.x; a2y += w[kk][2] * hv.y;
        }
        int j0 = jg * 3;
        part_l[0][kg][j0]   = a0x; part_l[1][kg][j0]   = a0y;
        part_l[0][kg][j0+1] = a1x; part_l[1][kg][j0+1] = a1y;
        part_l[0][kg][j0+2] = a2x; part_l[1][kg][j0+2] = a2y;
        __syncthreads();

        if (gb < 2) {
            float ghr = part_l[gb][0][gd]       + part_l[gb][1][gd]       + part_l[gb][2][gd]       + part_l[gb][3][gd];
            float ghi = part_l[gb][0][DIM+gd]   + part_l[gb][1][DIM+gd]   + part_l[gb][2][DIM+gd]   + part_l[gb][3][DIM+gd];
            float ghn = part_l[gb][0][2*DIM+gd] + part_l[gb][1][2*DIM+gd] + part_l[gb][2][2*DIM+gd] + part_l[gb][3][2*DIM+gd];
            float r  = sigmoidf_fast(gxr + ghr);
            float ig = sigmoidf_fast(gxi + ghi);
            float ng = tanhf_fast(gxn + r * ghn);
            float h  = h_l[gd * 2 + gb];
            float cc = conc_l[gb];
            float multi = (cc >= EPS_C ? cc : 0.f) * ig;
            float hnew = h + multi * (ng - h);
            h_l[gd * 2 + gb] = hnew;
            if (t == len_l[gb] - 1)
                hlast[(size_t)(b0 + gb) * G3 + p * DIM + gd] = hnew;
        }
        __syncthreads();
    }
}

// ---------------- K4 fallback (no gx buffer) ----------------
__global__ __launch_bounds__(384) void k_rnn(const int* __restrict__ seq,
                                             const int* __restrict__ lens,
                                             const float* __restrict__ emb,
                                             const float* __restrict__ g,
                                             const float* __restrict__ wxT,
                                             const float* __restrict__ whT,
                                             float* __restrict__ hlast) {
    int bid = blockIdx.x;
    int b0 = (bid & 63) * 4;
    int p = bid >> 6;
    __shared__ __align__(16) float h_l[DIM * 4];
    __shared__ __align__(16) float x_l[DIM * 4];
    __shared__ __align__(16) float sx_l[G3 * 4];
    __shared__ __align__(16) float sh_l[G3 * 4];
    __shared__ float conc_l[4];
    __shared__ int idx_l[4];
    __shared__ int len_l[4];
    int tid = threadIdx.x;
    if (tid < 4) len_l[tid] = lens[b0 + tid];
    for (int u = tid; u < DIM * 4; u += 384) h_l[u] = 0.f;
    __syncthreads();
    const float* wh = whT + (size_t)p * (DIM * G3);
    const float* wx = wxT + (size_t)p * (DIM * G3);
    for (int t = 0; t < SEQ; ++t) {
        if (tid < 4) {
            int ix = seq[t * NB + b0 + tid];
            idx_l[tid] = ix;
            conc_l[tid] = g[(size_t)ix * 3 + p];
        }
        __syncthreads();
        for (int u = tid; u < DIM * 4; u += 384) {
            int bc = u >> 7, k = u & 127;
            x_l[k * 4 + bc] = emb[(size_t)idx_l[bc] * DIM + k];
        }
        __syncthreads();
        int j = tid;
        float ax0 = 0.f, ax1 = 0.f, ax2 = 0.f, ax3 = 0.f;
#pragma unroll 4
        for (int k = 0; k < DIM; ++k) {
            float wv = wx[(size_t)k * G3 + j];
            float4 xv = *(const float4*)(x_l + k * 4);
            ax0 += wv * xv.x; ax1 += wv * xv.y; ax2 += wv * xv.z; ax3 += wv * xv.w;
        }
        float ah0 = 0.f, ah1 = 0.f, ah2 = 0.f, ah3 = 0.f;
#pragma unroll 4
        for (int k = 0; k < DIM; ++k) {
            float wv = wh[(size_t)k * G3 + j];
            float4 hv = *(const float4*)(h_l + k * 4);
            ah0 += wv * hv.x; ah1 += wv * hv.y; ah2 += wv * hv.z; ah3 += wv * hv.w;
        }
        *(float4*)(sx_l + j * 4) = make_float4(ax0, ax1, ax2, ax3);
        *(float4*)(sh_l + j * 4) = make_float4(ah0, ah1, ah2, ah3);
        __syncthreads();
        for (int u = tid; u < DIM * 4; u += 384) {
            int bc = u & 3, d = u >> 2;
            float sr = sx_l[d * 4 + bc] + sh_l[d * 4 + bc];
            float si = sx_l[(DIM + d) * 4 + bc] + sh_l[(DIM + d) * 4 + bc];
            float xn = sx_l[(2 * DIM + d) * 4 + bc];
            float hn = sh_l[(2 * DIM + d) * 4 + bc];
            float r  = sigmoidf_fast(sr);
            float ig = sigmoidf_fast(si);
            float ng = tanhf_fast(xn + r * hn);
            float h  = h_l[d * 4 + bc];
            float cc = conc_l[bc];
            float multi = (cc >= EPS_C ? cc : 0.f) * ig;
            float hnew = h + multi * (ng - h);
            h_l[d * 4 + bc] = hnew;
            if (t == len_l[bc] - 1)
                hlast[(size_t)(b0 + bc) * G3 + p * DIM + d] = hnew;
        }
        __syncthreads();
    }
}

// ---------------- K4.5: split hlast into bf16 hi/lo, packed in A-fragment order ----------------
// layout (elements): off = ks*8192 + b*32 + q*8 + j   (k = ks*32 + q*8 + j)
__global__ __launch_bounds__(256) void k_prep_h(const float* __restrict__ hlast,
                                                short* __restrict__ hl_hi,
                                                short* __restrict__ hl_lo) {
    int e = blockIdx.x * 256 + threadIdx.x;       // 98304
    int b = e / G3;
    int k = e % G3;
    float x = hlast[e];
    unsigned short hi = f2bf(x);
    unsigned short lo = f2bf(x - bf2f(hi));
    int off = (k >> 5) * 8192 + b * 32 + ((k >> 3) & 3) * 8 + (k & 7);
    hl_hi[off] = (short)hi;
    hl_lo[off] = (short)lo;
}

// ---------------- K5: logits via bf16 MFMA hi/lo (3-term), out = sigmoid ----------------
// grid = 1563 (i-tiles of 64). block = 256 = 4 waves; wave w owns b-strip w*64..+63.
// D = A(hlast,b x k) * B(scaled emb, k x i).  m->b, n->i.
__global__ __launch_bounds__(256) void k_logits_mfma(const float* __restrict__ emb,
                                                     const float* __restrict__ c,
                                                     const short* __restrict__ hl_hi,
                                                     const short* __restrict__ hl_lo,
                                                     float* __restrict__ out) {
    int i0 = blockIdx.x * 64;
    int tid = threadIdx.x;
    int w = tid >> 6;
    int lane = tid & 63;
    int n = lane & 15;       // i within 16-tile
    int q = lane >> 4;       // quad

    __shared__ __align__(16) float embs[64 * 132];   // [i][d] padded

    // stage emb tile (zero-fill OOB rows)
    for (int u = tid; u < 64 * 32; u += 256) {
        int i = u >> 5;
        int s = u & 31;                 // 16B segment -> d = s*4
        int gi = i0 + i;
        float4 v = make_float4(0.f, 0.f, 0.f, 0.f);
        if (gi < N_ITEMS) v = *(const float4*)(emb + (size_t)gi * DIM + s * 4);
        *(float4*)(embs + i * 132 + s * 4) = v;
    }

    // preload c scales: cv[is][p]
    float cv[4][3];
#pragma unroll
    for (int is = 0; is < 4; ++is) {
        int gi = i0 + is * 16 + n;
#pragma unroll
        for (int p = 0; p < 3; ++p)
            cv[is][p] = (gi < N_ITEMS) ? c[(size_t)gi * 3 + p] : 0.f;
    }
    __syncthreads();

    f32x4 acc[4][4];
#pragma unroll
    for (int bs = 0; bs < 4; ++bs)
#pragma unroll
        for (int is = 0; is < 4; ++is)
            acc[bs][is] = (f32x4){0.f, 0.f, 0.f, 0.f};

    for (int ks = 0; ks < 12; ++ks) {
        int p = ks >> 2;
        int d0 = (ks & 3) * 32;
        // A-frags from packed global (L2-resident)
        int abase = ks * 8192 + (w * 64 + n) * 32 + q * 8;
        s16x8 ah[4], al[4];
#pragma unroll
        for (int bs = 0; bs < 4; ++bs) {
            ah[bs] = *(const s16x8*)(hl_hi + abase + bs * 512);
            al[bs] = *(const s16x8*)(hl_lo + abase + bs * 512);
        }
#pragma unroll
        for (int is = 0; is < 4; ++is) {
            const float* src = embs + (is * 16 + n) * 132 + d0 + q * 8;
            float x[8];
            *(float4*)(x)     = *(const float4*)(src);
            *(float4*)(x + 4) = *(const float4*)(src + 4);
            float sc = cv[is][p];
            s16x8 bhv, blv;
#pragma unroll
            for (int j = 0; j < 8; ++j) {
                float v = x[j] * sc;
                unsigned short h = f2bf(v);
                bhv[j] = (short)h;
                blv[j] = (short)f2bf(v - bf2f(h));
            }
#pragma unroll
            for (int bs = 0; bs < 4; ++bs) {
                acc[bs][is] = __builtin_amdgcn_mfma_f32_16x16x32_bf16(ah[bs], blv, acc[bs][is], 0, 0, 0);
                acc[bs][is] = __builtin_amdgcn_mfma_f32_16x16x32_bf16(al[bs], bhv, acc[bs][is], 0, 0, 0);
                acc[bs][is] = __builtin_amdgcn_mfma_f32_16x16x32_bf16(ah[bs], bhv, acc[bs][is], 0, 0, 0);
            }
        }
    }

    // epilogue: D row = b = w*64 + bs*16 + q*4 + r ; col = i = i0 + is*16 + n
#pragma unroll
    for (int is = 0; is < 4; ++is) {
        int gi = i0 + is * 16 + n;
        if (gi >= N_ITEMS) continue;
#pragma unroll
        for (int bs = 0; bs < 4; ++bs) {
            int brow = w * 64 + bs * 16 + q * 4;
#pragma unroll
            for (int r = 0; r < 4; ++r)
                out[(size_t)(brow + r) * N_ITEMS + gi] = sigmoidf_fast(acc[bs][is][r]);
        }
    }
}

extern "C" void kernel_launch(void* const* d_in, const int* in_sizes, int n_in,
                              void* d_out, int out_size, void* d_ws, size_t ws_size,
                              hipStream_t stream) {
    const int*   seq  = (const int*)d_in[0];
    const int*   lens = (const int*)d_in[1];
    const float* emb  = (const float*)d_in[2];
    const float* pt   = (const float*)d_in[3];
    const float* x2h  = (const float*)d_in[4];
    const float* h2h  = (const float*)d_in[5];
    float* out = (float*)d_out;
    float* ws  = (float*)d_ws;

    float* g     = ws + OFF_G;
    float* c     = ws + OFF_C;
    float* wxT   = ws + OFF_WXT;
    float* whT   = ws + OFF_WHT;
    float* hlast = ws + OFF_HLAST;
    float* gxbuf = ws + OFF_GX;
    short* hl_hi = (short*)(ws + OFF_GX);       // aliases gx (dead after k_rnn2)
    short* hl_lo = hl_hi + 98304;

    int useGx = (ws_size >= (size_t)WS_FLOATS_PATHA * 4) ? 1 : 0;

    k_prep_w<<<576, 256, 0, stream>>>(x2h, h2h, wxT, whT);
    k_gc<<<3126, 256, 0, stream>>>(emb, pt, g, c);
    if (useGx) {
        k_gx<<<4800, 384, 0, stream>>>(seq, emb, wxT, gxbuf);
        k_rnn2<<<384, 512, 0, stream>>>(seq, lens, g, whT, gxbuf, hlast);
    } else {
        k_rnn<<<192, 384, 0, stream>>>(seq, lens, emb, g, wxT, whT, hlast);
    }
    k_prep_h<<<384, 256, 0, stream>>>(hlast, hl_hi, hl_lo);
    k_logits_mfma<<<1563, 256, 0, stream>>>(emb, c, hl_hi, hl_lo, out);
}

// Round 4
// 492.350 us; speedup vs baseline: 2.4094x; 1.3247x over previous
//
#include <hip/hip_runtime.h>
#include <hip/hip_bf16.h>
#include <math.h>

#define N_ITEMS 100001
#define DIM 128
#define NP 3
#define SEQ 100
#define NB 256
#define G3 384           // 3*DIM
#define TAU 0.1f
#define EPS_C 0.01f

// ---------------- ws layout (float offsets) ----------------
#define OFF_G     0
#define OFF_C     300016
#define OFF_WXT   600032
#define OFF_WHT   747488
#define OFF_HLAST 894944
#define OFF_GX    993248
// whA_hi/whA_lo (bf16 A-fragments of Wh) live in the OFF_WHT region (147456
// floats = exactly 2 x 147456 shorts). hl_hi/hl_lo alias the gx region.
#define WS_FLOATS_PATHA (993248 + 29491200)

typedef float f32x4 __attribute__((ext_vector_type(4)));
typedef short s16x8 __attribute__((ext_vector_type(8)));

__device__ __forceinline__ float sigmoidf_fast(float x) {
    return __builtin_amdgcn_rcpf(1.f + __builtin_amdgcn_exp2f(-1.4426950408889634f * x));
}
__device__ __forceinline__ float tanhf_fast(float x) {
    return 1.f - 2.f * __builtin_amdgcn_rcpf(1.f + __builtin_amdgcn_exp2f(2.8853900817779268f * x));
}
__device__ __forceinline__ unsigned short f2bf(float x) {
    union { float f; unsigned u; } v; v.f = x;
    unsigned r = v.u + 0x7fffu + ((v.u >> 16) & 1u);
    return (unsigned short)(r >> 16);
}
__device__ __forceinline__ float bf2f(unsigned short h) {
    union { unsigned u; float f; } v; v.u = ((unsigned)h) << 16;
    return v.f;
}

// ---------------- K1: transpose weights to [p][k][j] ----------------
__global__ void k_prep_w(const float* __restrict__ x2h, const float* __restrict__ h2h,
                         float* __restrict__ wxT, float* __restrict__ whT) {
    int idx = blockIdx.x * 256 + threadIdx.x;
    if (idx >= NP * DIM * G3) return;
    int j = idx % G3;
    int k = (idx / G3) % DIM;
    int p = idx / (G3 * DIM);
    wxT[idx] = x2h[((size_t)p * G3 + j) * DIM + k];
    whT[idx] = h2h[((size_t)p * G3 + j) * DIM + k];
}

// ---------------- K1b: Wh -> bf16 hi/lo A-fragments ----------------
// frag e = ((p*24 + mt)*4 + ks)*64 + lane ; holds Wh[p][mt*16 + (lane&15)]
// [ks*32 + (lane>>4)*8 + 0..7]  (8 contiguous d -> one s16x8)
__global__ __launch_bounds__(256) void k_prep_whA(const float* __restrict__ h2h,
                                                  short* __restrict__ whA_hi,
                                                  short* __restrict__ whA_lo) {
    int e = blockIdx.x * 256 + threadIdx.x;       // 3*24*4*64 = 18432
    if (e >= NP * 24 * 4 * 64) return;
    int lane = e & 63;
    int ks = (e >> 6) & 3;
    int mt = (e >> 8) % 24;
    int p  = e / 6144;
    int j = mt * 16 + (lane & 15);
    int d = ks * 32 + (lane >> 4) * 8;
    const float* src = h2h + ((size_t)p * G3 + j) * DIM + d;
    short hi[8], lo[8];
#pragma unroll
    for (int u = 0; u < 8; ++u) {
        float x = src[u];
        unsigned short h = f2bf(x);
        hi[u] = (short)h;
        lo[u] = (short)f2bf(x - bf2f(h));
    }
    *(s16x8*)(whA_hi + (size_t)e * 8) = *(const s16x8*)hi;
    *(s16x8*)(whA_lo + (size_t)e * 8) = *(const s16x8*)lo;
}

// ---------------- K2: per-item norm + softmax(g) + c = g/norm ----------------
__global__ __launch_bounds__(256) void k_gc(const float* __restrict__ emb,
                                            const float* __restrict__ pt,
                                            float* __restrict__ g, float* __restrict__ c) {
    __shared__ float pt_l[G3];
    __shared__ float ainv[NP];
    int tid = threadIdx.x;
    for (int u = tid; u < G3; u += 256) pt_l[u] = pt[u];
    __syncthreads();
    if (tid < NP) {
        float ss = 0.f;
        for (int k = 0; k < DIM; ++k) { float v = pt_l[tid * DIM + k]; ss += v * v; }
        ainv[tid] = 1.f / fmaxf(sqrtf(ss), 1e-12f);
    }
    __syncthreads();
    int lane = tid & 63, wv = tid >> 6;
    for (int it = 0; it < 8; ++it) {
        int i = blockIdx.x * 32 + wv * 8 + it;
        if (i >= N_ITEMS) continue;
        float a = emb[(size_t)i * DIM + lane];
        float b = emb[(size_t)i * DIM + 64 + lane];
        float ss = a * a + b * b;
        float d0 = a * pt_l[lane]       + b * pt_l[64 + lane];
        float d1 = a * pt_l[128 + lane] + b * pt_l[192 + lane];
        float d2 = a * pt_l[256 + lane] + b * pt_l[320 + lane];
        for (int off = 32; off > 0; off >>= 1) {
            ss += __shfl_down(ss, off);
            d0 += __shfl_down(d0, off);
            d1 += __shfl_down(d1, off);
            d2 += __shfl_down(d2, off);
        }
        if (lane == 0) {
            if (i == 0) {
                g[0] = 0.f; g[1] = 0.f; g[2] = 0.f;
                c[0] = 0.f; c[1] = 0.f; c[2] = 0.f;
            } else {
                float inv = 1.f / fmaxf(sqrtf(ss), 1e-12f);
                float l0 = d0 * ainv[0] * inv * (1.f / TAU);
                float l1 = d1 * ainv[1] * inv * (1.f / TAU);
                float l2 = d2 * ainv[2] * inv * (1.f / TAU);
                float m = fmaxf(l0, fmaxf(l1, l2));
                float e0 = expf(l0 - m), e1 = expf(l1 - m), e2 = expf(l2 - m);
                float is = 1.f / (e0 + e1 + e2);
                float g0 = e0 * is, g1 = e1 * is, g2 = e2 * is;
                g[(size_t)i * 3 + 0] = g0; g[(size_t)i * 3 + 1] = g1; g[(size_t)i * 3 + 2] = g2;
                c[(size_t)i * 3 + 0] = g0 * inv; c[(size_t)i * 3 + 1] = g1 * inv; c[(size_t)i * 3 + 2] = g2 * inv;
            }
        }
    }
}

// ---------------- K3 (path A): Gx[t][p][b][j] ----------------
__global__ __launch_bounds__(384) void k_gx(const int* __restrict__ seq,
                                            const float* __restrict__ emb,
                                            const float* __restrict__ wxT,
                                            float* __restrict__ gx) {
    int bid = blockIdx.x;               // 100*3*16 = 4800
    int bch = bid & 15;
    int p = (bid >> 4) % 3;
    int t = bid / 48;
    int b0 = bch * 16;
    __shared__ int idx_l[16];
    __shared__ __align__(16) float x_l[DIM * 16];
    int tid = threadIdx.x;
    if (tid < 16) idx_l[tid] = seq[t * NB + b0 + tid];
    __syncthreads();
    for (int u = tid; u < DIM * 16; u += 384) {
        int bc = u >> 7, k = u & 127;
        x_l[k * 16 + bc] = emb[(size_t)idx_l[bc] * DIM + k];
    }
    __syncthreads();
    int j = tid;
    float acc[16];
#pragma unroll
    for (int q = 0; q < 16; ++q) acc[q] = 0.f;
    const float* w = wxT + (size_t)p * (DIM * G3) + j;
#pragma unroll 2
    for (int k = 0; k < DIM; ++k) {
        float wv = w[(size_t)k * G3];
        const float4* xp = (const float4*)(x_l + k * 16);
        float4 x0 = xp[0], x1 = xp[1], x2 = xp[2], x3 = xp[3];
        acc[0]  += wv * x0.x; acc[1]  += wv * x0.y; acc[2]  += wv * x0.z; acc[3]  += wv * x0.w;
        acc[4]  += wv * x1.x; acc[5]  += wv * x1.y; acc[6]  += wv * x1.z; acc[7]  += wv * x1.w;
        acc[8]  += wv * x2.x; acc[9]  += wv * x2.y; acc[10] += wv * x2.z; acc[11] += wv * x2.w;
        acc[12] += wv * x3.x; acc[13] += wv * x3.y; acc[14] += wv * x3.z; acc[15] += wv * x3.w;
    }
    float* o = gx + ((size_t)(t * 3 + p) * NB + b0) * G3 + j;
#pragma unroll
    for (int bc = 0; bc < 16; ++bc) o[(size_t)bc * G3] = acc[bc];
}

// ---------------- K4 v3: MFMA recurrence ----------------
// grid 48 = 3p * 16 b-tiles(16).  block 512 = 8 waves; wave w owns m-tiles
// {w, w+8, w+16} so the (r,i,n) gate triple for d in [w*16,w*16+16) is in-lane.
// h state in LDS as bf16 hi/lo B-fragments, double buffered.
__global__ __launch_bounds__(512, 2) void k_rnn3(const int* __restrict__ seq,
                                                 const int* __restrict__ lens,
                                                 const float* __restrict__ g,
                                                 const short* __restrict__ whA_hi,
                                                 const short* __restrict__ whA_lo,
                                                 const float* __restrict__ gx,
                                                 float* __restrict__ hlast) {
    int bid = blockIdx.x;
    int p  = bid / 16;
    int b0 = (bid % 16) * 16;
    int tid = threadIdx.x;
    int lane = tid & 63;
    int w = tid >> 6;
    int n = lane & 15;
    int q = lane >> 4;
    int d0 = w * 16 + q * 4;

    __shared__ __align__(16) unsigned short hH[2 * 2048];   // [buf][ks*512 + lane*8 + jj]
    __shared__ __align__(16) unsigned short hL[2 * 2048];
    __shared__ float conc_s[SEQ * 16];

    for (int u = tid; u < 2048; u += 512) { hH[u] = 0; hL[u] = 0; }

    // conc table for all steps (thresholded)
    for (int e = tid; e < SEQ * 16; e += 512) {
        int t = e >> 4, b = e & 15;
        int ix = seq[t * NB + b0 + b];
        float cc = g[(size_t)ix * 3 + p];
        conc_s[e] = (cc >= EPS_C) ? cc : 0.f;
    }

    // Wh A-fragments into registers (hi/lo)
    s16x8 whH[3][4], whL[3][4];
    int mts0 = w, mts1 = 8 + w, mts2 = 16 + w;
#pragma unroll
    for (int ks = 0; ks < 4; ++ks) {
        size_t o0 = ((((size_t)p * 24 + mts0) * 4 + ks) * 64 + lane) * 8;
        size_t o1 = ((((size_t)p * 24 + mts1) * 4 + ks) * 64 + lane) * 8;
        size_t o2 = ((((size_t)p * 24 + mts2) * 4 + ks) * 64 + lane) * 8;
        whH[0][ks] = *(const s16x8*)(whA_hi + o0);
        whH[1][ks] = *(const s16x8*)(whA_hi + o1);
        whH[2][ks] = *(const s16x8*)(whA_hi + o2);
        whL[0][ks] = *(const s16x8*)(whA_lo + o0);
        whL[1][ks] = *(const s16x8*)(whA_lo + o1);
        whL[2][ks] = *(const s16x8*)(whA_lo + o2);
    }

    int len_n = lens[b0 + n];
    float h0 = 0.f, h1 = 0.f, h2 = 0.f, h3 = 0.f;

    // writer address: d0..d0+3 land at buffer idx wks*512 + rl*8 + jj0 (+0..3)
    int wks = d0 >> 5;
    int km  = d0 & 31;
    int rl  = (km >> 3) * 16 + n;
    int jj0 = km & 7;                 // 0 or 4
    int widx = wks * 512 + rl * 8 + jj0;

    const float* gxbase = gx + ((size_t)p * NB + (b0 + n)) * G3 + d0;
    const size_t tstride = (size_t)3 * NB * G3;

    f32x4 pgr = *(const f32x4*)(gxbase);
    f32x4 pgi = *(const f32x4*)(gxbase + DIM);
    f32x4 pgn = *(const f32x4*)(gxbase + 2 * DIM);

    __syncthreads();

    int cur = 0;
    for (int t = 0; t < SEQ; ++t) {
        f32x4 grv = pgr, giv = pgi, gnv = pgn;
        int tn = (t + 1 < SEQ) ? (t + 1) : t;
        const float* gp = gxbase + (size_t)tn * tstride;
        pgr = *(const f32x4*)(gp);
        pgi = *(const f32x4*)(gp + DIM);
        pgn = *(const f32x4*)(gp + 2 * DIM);

        float cc = conc_s[t * 16 + n];

        f32x4 acc0 = {0.f,0.f,0.f,0.f}, acc1 = {0.f,0.f,0.f,0.f}, acc2 = {0.f,0.f,0.f,0.f};
        const s16x8* bhp = (const s16x8*)hH + cur * 256 + lane;
        const s16x8* blp = (const s16x8*)hL + cur * 256 + lane;
#pragma unroll
        for (int ks = 0; ks < 4; ++ks) {
            s16x8 bh = bhp[ks * 64];
            s16x8 bl = blp[ks * 64];
            acc0 = __builtin_amdgcn_mfma_f32_16x16x32_bf16(whH[0][ks], bl, acc0, 0, 0, 0);
            acc1 = __builtin_amdgcn_mfma_f32_16x16x32_bf16(whH[1][ks], bl, acc1, 0, 0, 0);
            acc2 = __builtin_amdgcn_mfma_f32_16x16x32_bf16(whH[2][ks], bl, acc2, 0, 0, 0);
            acc0 = __builtin_amdgcn_mfma_f32_16x16x32_bf16(whL[0][ks], bh, acc0, 0, 0, 0);
            acc1 = __builtin_amdgcn_mfma_f32_16x16x32_bf16(whL[1][ks], bh, acc1, 0, 0, 0);
            acc2 = __builtin_amdgcn_mfma_f32_16x16x32_bf16(whL[2][ks], bh, acc2, 0, 0, 0);
            acc0 = __builtin_amdgcn_mfma_f32_16x16x32_bf16(whH[0][ks], bh, acc0, 0, 0, 0);
            acc1 = __builtin_amdgcn_mfma_f32_16x16x32_bf16(whH[1][ks], bh, acc1, 0, 0, 0);
            acc2 = __builtin_amdgcn_mfma_f32_16x16x32_bf16(whH[2][ks], bh, acc2, 0, 0, 0);
        }

        float ar[4], ai[4], an[4], gr4[4], gi4[4], gn4[4];
        *(f32x4*)ar = acc0; *(f32x4*)ai = acc1; *(f32x4*)an = acc2;
        *(f32x4*)gr4 = grv; *(f32x4*)gi4 = giv; *(f32x4*)gn4 = gnv;
        float hh[4] = {h0, h1, h2, h3};
        float hnew[4];
#pragma unroll
        for (int r = 0; r < 4; ++r) {
            float rr = sigmoidf_fast(gr4[r] + ar[r]);
            float ig = sigmoidf_fast(gi4[r] + ai[r]);
            float ng = tanhf_fast(gn4[r] + rr * an[r]);
            float m2 = cc * ig;
            hnew[r] = hh[r] + m2 * (ng - hh[r]);
        }
        h0 = hnew[0]; h1 = hnew[1]; h2 = hnew[2]; h3 = hnew[3];

        if (t == len_n - 1) {
            float* hp = hlast + (size_t)(b0 + n) * G3 + p * DIM + d0;
            *(float4*)hp = make_float4(h0, h1, h2, h3);
        }

        // split hnew -> hi/lo, write to other buffer
        unsigned short sh[4], sl[4];
#pragma unroll
        for (int r = 0; r < 4; ++r) {
            sh[r] = f2bf(hnew[r]);
            sl[r] = f2bf(hnew[r] - bf2f(sh[r]));
        }
        int wb = (cur ^ 1) * 2048 + widx;
        unsigned hw0 = (unsigned)sh[0] | ((unsigned)sh[1] << 16);
        unsigned hw1 = (unsigned)sh[2] | ((unsigned)sh[3] << 16);
        unsigned lw0 = (unsigned)sl[0] | ((unsigned)sl[1] << 16);
        unsigned lw1 = (unsigned)sl[2] | ((unsigned)sl[3] << 16);
        *(uint2*)(hH + wb) = make_uint2(hw0, hw1);
        *(uint2*)(hL + wb) = make_uint2(lw0, lw1);
        __syncthreads();
        cur ^= 1;
    }
}

// ---------------- K4 fallback (no gx buffer) ----------------
__global__ __launch_bounds__(384) void k_rnn(const int* __restrict__ seq,
                                             const int* __restrict__ lens,
                                             const float* __restrict__ emb,
                                             const float* __restrict__ g,
                                             const float* __restrict__ wxT,
                                             const float* __restrict__ whT,
                                             float* __restrict__ hlast) {
    int bid = blockIdx.x;
    int b0 = (bid & 63) * 4;
    int p = bid >> 6;
    __shared__ __align__(16) float h_l[DIM * 4];
    __shared__ __align__(16) float x_l[DIM * 4];
    __shared__ __align__(16) float sx_l[G3 * 4];
    __shared__ __align__(16) float sh_l[G3 * 4];
    __shared__ float conc_l[4];
    __shared__ int idx_l[4];
    __shared__ int len_l[4];
    int tid = threadIdx.x;
    if (tid < 4) len_l[tid] = lens[b0 + tid];
    for (int u = tid; u < DIM * 4; u += 384) h_l[u] = 0.f;
    __syncthreads();
    const float* wh = whT + (size_t)p * (DIM * G3);
    const float* wx = wxT + (size_t)p * (DIM * G3);
    for (int t = 0; t < SEQ; ++t) {
        if (tid < 4) {
            int ix = seq[t * NB + b0 + tid];
            idx_l[tid] = ix;
            conc_l[tid] = g[(size_t)ix * 3 + p];
        }
        __syncthreads();
        for (int u = tid; u < DIM * 4; u += 384) {
            int bc = u >> 7, k = u & 127;
            x_l[k * 4 + bc] = emb[(size_t)idx_l[bc] * DIM + k];
        }
        __syncthreads();
        int j = tid;
        float ax0 = 0.f, ax1 = 0.f, ax2 = 0.f, ax3 = 0.f;
#pragma unroll 4
        for (int k = 0; k < DIM; ++k) {
            float wv = wx[(size_t)k * G3 + j];
            float4 xv = *(const float4*)(x_l + k * 4);
            ax0 += wv * xv.x; ax1 += wv * xv.y; ax2 += wv * xv.z; ax3 += wv * xv.w;
        }
        float ah0 = 0.f, ah1 = 0.f, ah2 = 0.f, ah3 = 0.f;
#pragma unroll 4
        for (int k = 0; k < DIM; ++k) {
            float wv = wh[(size_t)k * G3 + j];
            float4 hv = *(const float4*)(h_l + k * 4);
            ah0 += wv * hv.x; ah1 += wv * hv.y; ah2 += wv * hv.z; ah3 += wv * hv.w;
        }
        *(float4*)(sx_l + j * 4) = make_float4(ax0, ax1, ax2, ax3);
        *(float4*)(sh_l + j * 4) = make_float4(ah0, ah1, ah2, ah3);
        __syncthreads();
        for (int u = tid; u < DIM * 4; u += 384) {
            int bc = u & 3, d = u >> 2;
            float sr = sx_l[d * 4 + bc] + sh_l[d * 4 + bc];
            float si = sx_l[(DIM + d) * 4 + bc] + sh_l[(DIM + d) * 4 + bc];
            float xn = sx_l[(2 * DIM + d) * 4 + bc];
            float hn = sh_l[(2 * DIM + d) * 4 + bc];
            float r  = sigmoidf_fast(sr);
            float ig = sigmoidf_fast(si);
            float ng = tanhf_fast(xn + r * hn);
            float h  = h_l[d * 4 + bc];
            float cc = conc_l[bc];
            float multi = (cc >= EPS_C ? cc : 0.f) * ig;
            float hnew = h + multi * (ng - h);
            h_l[d * 4 + bc] = hnew;
            if (t == len_l[bc] - 1)
                hlast[(size_t)(b0 + bc) * G3 + p * DIM + d] = hnew;
        }
        __syncthreads();
    }
}

// ---------------- K4.5: split hlast into bf16 hi/lo, packed in A-fragment order ----------------
__global__ __launch_bounds__(256) void k_prep_h(const float* __restrict__ hlast,
                                                short* __restrict__ hl_hi,
                                                short* __restrict__ hl_lo) {
    int e = blockIdx.x * 256 + threadIdx.x;       // 98304
    int b = e / G3;
    int k = e % G3;
    float x = hlast[e];
    unsigned short hi = f2bf(x);
    unsigned short lo = f2bf(x - bf2f(hi));
    int off = (k >> 5) * 8192 + b * 32 + ((k >> 3) & 3) * 8 + (k & 7);
    hl_hi[off] = (short)hi;
    hl_lo[off] = (short)lo;
}

// ---------------- K5: logits via bf16 MFMA hi/lo (3-term), out = sigmoid ----------------
__global__ __launch_bounds__(256) void k_logits_mfma(const float* __restrict__ emb,
                                                     const float* __restrict__ c,
                                                     const short* __restrict__ hl_hi,
                                                     const short* __restrict__ hl_lo,
                                                     float* __restrict__ out) {
    int i0 = blockIdx.x * 64;
    int tid = threadIdx.x;
    int w = tid >> 6;
    int lane = tid & 63;
    int n = lane & 15;
    int q = lane >> 4;

    __shared__ __align__(16) float embs[64 * 132];

    for (int u = tid; u < 64 * 32; u += 256) {
        int i = u >> 5;
        int s = u & 31;
        int gi = i0 + i;
        float4 v = make_float4(0.f, 0.f, 0.f, 0.f);
        if (gi < N_ITEMS) v = *(const float4*)(emb + (size_t)gi * DIM + s * 4);
        *(float4*)(embs + i * 132 + s * 4) = v;
    }

    float cv[4][3];
#pragma unroll
    for (int is = 0; is < 4; ++is) {
        int gi = i0 + is * 16 + n;
#pragma unroll
        for (int p = 0; p < 3; ++p)
            cv[is][p] = (gi < N_ITEMS) ? c[(size_t)gi * 3 + p] : 0.f;
    }
    __syncthreads();

    f32x4 acc[4][4];
#pragma unroll
    for (int bs = 0; bs < 4; ++bs)
#pragma unroll
        for (int is = 0; is < 4; ++is)
            acc[bs][is] = (f32x4){0.f, 0.f, 0.f, 0.f};

    for (int ks = 0; ks < 12; ++ks) {
        int p = ks >> 2;
        int d0 = (ks & 3) * 32;
        int abase = ks * 8192 + (w * 64 + n) * 32 + q * 8;
        s16x8 ah[4], al[4];
#pragma unroll
        for (int bs = 0; bs < 4; ++bs) {
            ah[bs] = *(const s16x8*)(hl_hi + abase + bs * 512);
            al[bs] = *(const s16x8*)(hl_lo + abase + bs * 512);
        }
#pragma unroll
        for (int is = 0; is < 4; ++is) {
            const float* src = embs + (is * 16 + n) * 132 + d0 + q * 8;
            float x[8];
            *(float4*)(x)     = *(const float4*)(src);
            *(float4*)(x + 4) = *(const float4*)(src + 4);
            float sc = cv[is][p];
            s16x8 bhv, blv;
#pragma unroll
            for (int j = 0; j < 8; ++j) {
                float v = x[j] * sc;
                unsigned short h = f2bf(v);
                bhv[j] = (short)h;
                blv[j] = (short)f2bf(v - bf2f(h));
            }
#pragma unroll
            for (int bs = 0; bs < 4; ++bs) {
                acc[bs][is] = __builtin_amdgcn_mfma_f32_16x16x32_bf16(ah[bs], blv, acc[bs][is], 0, 0, 0);
                acc[bs][is] = __builtin_amdgcn_mfma_f32_16x16x32_bf16(al[bs], bhv, acc[bs][is], 0, 0, 0);
                acc[bs][is] = __builtin_amdgcn_mfma_f32_16x16x32_bf16(ah[bs], bhv, acc[bs][is], 0, 0, 0);
            }
        }
    }

#pragma unroll
    for (int is = 0; is < 4; ++is) {
        int gi = i0 + is * 16 + n;
        if (gi >= N_ITEMS) continue;
#pragma unroll
        for (int bs = 0; bs < 4; ++bs) {
            int brow = w * 64 + bs * 16 + q * 4;
#pragma unroll
            for (int r = 0; r < 4; ++r)
                out[(size_t)(brow + r) * N_ITEMS + gi] = sigmoidf_fast(acc[bs][is][r]);
        }
    }
}

extern "C" void kernel_launch(void* const* d_in, const int* in_sizes, int n_in,
                              void* d_out, int out_size, void* d_ws, size_t ws_size,
                              hipStream_t stream) {
    const int*   seq  = (const int*)d_in[0];
    const int*   lens = (const int*)d_in[1];
    const float* emb  = (const float*)d_in[2];
    const float* pt   = (const float*)d_in[3];
    const float* x2h  = (const float*)d_in[4];
    const float* h2h  = (const float*)d_in[5];
    float* out = (float*)d_out;
    float* ws  = (float*)d_ws;

    float* g     = ws + OFF_G;
    float* c     = ws + OFF_C;
    float* wxT   = ws + OFF_WXT;
    float* whT   = ws + OFF_WHT;
    float* hlast = ws + OFF_HLAST;
    float* gxbuf = ws + OFF_GX;
    short* whA_hi = (short*)(ws + OFF_WHT);     // overwrites whT (unused in useGx path)
    short* whA_lo = whA_hi + 147456;
    short* hl_hi = (short*)(ws + OFF_GX);       // aliases gx (dead after k_rnn3)
    short* hl_lo = hl_hi + 98304;

    int useGx = (ws_size >= (size_t)WS_FLOATS_PATHA * 4) ? 1 : 0;

    k_prep_w<<<576, 256, 0, stream>>>(x2h, h2h, wxT, whT);
    k_gc<<<3126, 256, 0, stream>>>(emb, pt, g, c);
    if (useGx) {
        k_prep_whA<<<72, 256, 0, stream>>>(h2h, whA_hi, whA_lo);
        k_gx<<<4800, 384, 0, stream>>>(seq, emb, wxT, gxbuf);
        k_rnn3<<<48, 512, 0, stream>>>(seq, lens, g, whA_hi, whA_lo, gxbuf, hlast);
    } else {
        k_rnn<<<192, 384, 0, stream>>>(seq, lens, emb, g, wxT, whT, hlast);
    }
    k_prep_h<<<384, 256, 0, stream>>>(hlast, hl_hi, hl_lo);
    k_logits_mfma<<<1563, 256, 0, stream>>>(emb, c, hl_hi, hl_lo, out);
}

// Round 5
// 409.403 us; speedup vs baseline: 2.8975x; 1.2026x over previous
//
#include <hip/hip_runtime.h>
#include <hip/hip_bf16.h>
#include <math.h>

#define N_ITEMS 100001
#define DIM 128
#define NP 3
#define SEQ 100
#define NB 256
#define G3 384           // 3*DIM
#define TAU 0.1f
#define EPS_C 0.01f

// ---------------- ws layout (float offsets) ----------------
#define OFF_G     0
#define OFF_C     300016
#define OFF_WXT   600032
#define OFF_WHT   747488
#define OFF_HLAST 894944
#define OFF_GX    993248
// useGx path: wxA_hi/lo (bf16 A-frags of Wx) fill the OFF_WXT region
// (2 x 147456 shorts = 147456 floats), whA_hi/lo fill OFF_WHT likewise.
// hl_hi/hl_lo alias the gx region (dead after k_rnn3).
#define WS_FLOATS_PATHA (993248 + 29491200)

typedef float f32x4 __attribute__((ext_vector_type(4)));
typedef short s16x8 __attribute__((ext_vector_type(8)));

__device__ __forceinline__ float sigmoidf_fast(float x) {
    return __builtin_amdgcn_rcpf(1.f + __builtin_amdgcn_exp2f(-1.4426950408889634f * x));
}
__device__ __forceinline__ float tanhf_fast(float x) {
    return 1.f - 2.f * __builtin_amdgcn_rcpf(1.f + __builtin_amdgcn_exp2f(2.8853900817779268f * x));
}
__device__ __forceinline__ unsigned short f2bf(float x) {
    union { float f; unsigned u; } v; v.f = x;
    unsigned r = v.u + 0x7fffu + ((v.u >> 16) & 1u);
    return (unsigned short)(r >> 16);
}
__device__ __forceinline__ float bf2f(unsigned short h) {
    union { unsigned u; float f; } v; v.u = ((unsigned)h) << 16;
    return v.f;
}

// ---------------- K1 (fallback only): transpose weights to [p][k][j] ----------------
__global__ void k_prep_w(const float* __restrict__ x2h, const float* __restrict__ h2h,
                         float* __restrict__ wxT, float* __restrict__ whT) {
    int idx = blockIdx.x * 256 + threadIdx.x;
    if (idx >= NP * DIM * G3) return;
    int j = idx % G3;
    int k = (idx / G3) % DIM;
    int p = idx / (G3 * DIM);
    wxT[idx] = x2h[((size_t)p * G3 + j) * DIM + k];
    whT[idx] = h2h[((size_t)p * G3 + j) * DIM + k];
}

// ---------------- K1b: Wx AND Wh -> bf16 hi/lo A-fragments ----------------
// frag f = ((p*24 + mt)*4 + ks)*64 + lane ; holds W[p][mt*16 + (lane&15)]
// [ks*32 + (lane>>4)*8 + 0..7]
__global__ __launch_bounds__(256) void k_prep_wA(const float* __restrict__ x2h,
                                                 const float* __restrict__ h2h,
                                                 short* __restrict__ wxA_hi,
                                                 short* __restrict__ wxA_lo,
                                                 short* __restrict__ whA_hi,
                                                 short* __restrict__ whA_lo) {
    int e = blockIdx.x * 256 + threadIdx.x;       // 2*18432 = 36864
    if (e >= 2 * NP * 24 * 4 * 64) return;
    int which = (e >= NP * 24 * 4 * 64);
    int f = which ? e - NP * 24 * 4 * 64 : e;
    const float* tab = which ? h2h : x2h;
    short* dh = which ? whA_hi : wxA_hi;
    short* dl = which ? whA_lo : wxA_lo;
    int lane = f & 63;
    int ks = (f >> 6) & 3;
    int mt = (f >> 8) % 24;
    int p  = f / 6144;
    int j = mt * 16 + (lane & 15);
    int d = ks * 32 + (lane >> 4) * 8;
    const float* src = tab + ((size_t)p * G3 + j) * DIM + d;
    short hi[8], lo[8];
#pragma unroll
    for (int u = 0; u < 8; ++u) {
        float x = src[u];
        unsigned short h = f2bf(x);
        hi[u] = (short)h;
        lo[u] = (short)f2bf(x - bf2f(h));
    }
    *(s16x8*)(dh + (size_t)f * 8) = *(const s16x8*)hi;
    *(s16x8*)(dl + (size_t)f * 8) = *(const s16x8*)lo;
}

// ---------------- K2: per-item norm + softmax(g) + c = g/norm ----------------
__global__ __launch_bounds__(256) void k_gc(const float* __restrict__ emb,
                                            const float* __restrict__ pt,
                                            float* __restrict__ g, float* __restrict__ c) {
    __shared__ float pt_l[G3];
    __shared__ float ainv[NP];
    int tid = threadIdx.x;
    for (int u = tid; u < G3; u += 256) pt_l[u] = pt[u];
    __syncthreads();
    if (tid < NP) {
        float ss = 0.f;
        for (int k = 0; k < DIM; ++k) { float v = pt_l[tid * DIM + k]; ss += v * v; }
        ainv[tid] = 1.f / fmaxf(sqrtf(ss), 1e-12f);
    }
    __syncthreads();
    int lane = tid & 63, wv = tid >> 6;
    for (int it = 0; it < 8; ++it) {
        int i = blockIdx.x * 32 + wv * 8 + it;
        if (i >= N_ITEMS) continue;
        float a = emb[(size_t)i * DIM + lane];
        float b = emb[(size_t)i * DIM + 64 + lane];
        float ss = a * a + b * b;
        float d0 = a * pt_l[lane]       + b * pt_l[64 + lane];
        float d1 = a * pt_l[128 + lane] + b * pt_l[192 + lane];
        float d2 = a * pt_l[256 + lane] + b * pt_l[320 + lane];
        for (int off = 32; off > 0; off >>= 1) {
            ss += __shfl_down(ss, off);
            d0 += __shfl_down(d0, off);
            d1 += __shfl_down(d1, off);
            d2 += __shfl_down(d2, off);
        }
        if (lane == 0) {
            if (i == 0) {
                g[0] = 0.f; g[1] = 0.f; g[2] = 0.f;
                c[0] = 0.f; c[1] = 0.f; c[2] = 0.f;
            } else {
                float inv = 1.f / fmaxf(sqrtf(ss), 1e-12f);
                float l0 = d0 * ainv[0] * inv * (1.f / TAU);
                float l1 = d1 * ainv[1] * inv * (1.f / TAU);
                float l2 = d2 * ainv[2] * inv * (1.f / TAU);
                float m = fmaxf(l0, fmaxf(l1, l2));
                float e0 = expf(l0 - m), e1 = expf(l1 - m), e2 = expf(l2 - m);
                float is = 1.f / (e0 + e1 + e2);
                float g0 = e0 * is, g1 = e1 * is, g2 = e2 * is;
                g[(size_t)i * 3 + 0] = g0; g[(size_t)i * 3 + 1] = g1; g[(size_t)i * 3 + 2] = g2;
                c[(size_t)i * 3 + 0] = g0 * inv; c[(size_t)i * 3 + 1] = g1 * inv; c[(size_t)i * 3 + 2] = g2 * inv;
            }
        }
    }
}

// ---------------- K3 v2: Gx via MFMA ----------------
// grid 1600 = 100 t * 16 token-tiles(16). block 512 = 8 waves.
// Stage 16 emb rows as bf16 hi/lo B-fragments in LDS once; waves sweep
// 72 (p, mt) jobs, A-frags streamed from L2-resident wxA tables.
__global__ __launch_bounds__(512, 2) void k_gx_mfma(const int* __restrict__ seq,
                                                    const float* __restrict__ emb,
                                                    const short* __restrict__ wxA_hi,
                                                    const short* __restrict__ wxA_lo,
                                                    float* __restrict__ gx) {
    int bid = blockIdx.x;
    int t  = bid >> 4;
    int b0 = (bid & 15) * 16;
    int tid = threadIdx.x;
    int lane = tid & 63;
    int w = tid >> 6;
    int n = lane & 15;
    int q = lane >> 4;

    __shared__ int idx_l[16];
    __shared__ __align__(16) unsigned short xH[2048];   // [ks*512 + lane*8 + j]
    __shared__ __align__(16) unsigned short xL[2048];

    if (tid < 16) idx_l[tid] = seq[t * NB + b0 + tid];
    __syncthreads();

    // stage x fragments: thread -> (token tk, float4 segment s)
    {
        int tk = tid >> 5, s = tid & 31;
        float4 v = *(const float4*)(emb + (size_t)idx_l[tk] * DIM + s * 4);
        int k = s * 4;
        int ks = k >> 5, km = k & 31;
        int ln = (km >> 3) * 16 + tk;
        int j0 = km & 7;                  // 0 or 4
        int o = ks * 512 + ln * 8 + j0;
        float xv[4] = {v.x, v.y, v.z, v.w};
        unsigned short sh[4], sl[4];
#pragma unroll
        for (int r = 0; r < 4; ++r) {
            sh[r] = f2bf(xv[r]);
            sl[r] = f2bf(xv[r] - bf2f(sh[r]));
        }
        *(uint2*)(xH + o) = make_uint2((unsigned)sh[0] | ((unsigned)sh[1] << 16),
                                       (unsigned)sh[2] | ((unsigned)sh[3] << 16));
        *(uint2*)(xL + o) = make_uint2((unsigned)sl[0] | ((unsigned)sl[1] << 16),
                                       (unsigned)sl[2] | ((unsigned)sl[3] << 16));
    }
    __syncthreads();

    // B-frags for this lane (all 4 k-slices) — register-resident
    s16x8 bh[4], bl[4];
#pragma unroll
    for (int ks = 0; ks < 4; ++ks) {
        bh[ks] = ((const s16x8*)xH)[ks * 64 + lane];
        bl[ks] = ((const s16x8*)xL)[ks * 64 + lane];
    }

    float* gxt = gx + (size_t)(t * 3) * NB * G3;
#pragma unroll 3
    for (int ji = 0; ji < 9; ++ji) {
        int pid = w + ji * 8;           // 0..71
        int p = pid / 24, mt = pid % 24;
        f32x4 acc = {0.f, 0.f, 0.f, 0.f};
#pragma unroll
        for (int ks = 0; ks < 4; ++ks) {
            size_t ao = ((((size_t)p * 24 + mt) * 4 + ks) * 64 + lane) * 8;
            s16x8 ah = *(const s16x8*)(wxA_hi + ao);
            s16x8 al = *(const s16x8*)(wxA_lo + ao);
            acc = __builtin_amdgcn_mfma_f32_16x16x32_bf16(ah, bl[ks], acc, 0, 0, 0);
            acc = __builtin_amdgcn_mfma_f32_16x16x32_bf16(al, bh[ks], acc, 0, 0, 0);
            acc = __builtin_amdgcn_mfma_f32_16x16x32_bf16(ah, bh[ks], acc, 0, 0, 0);
        }
        // D: row = q*4+r -> j = mt*16 + q*4 + r ; col = n -> token b0+n
        float* o = gxt + ((size_t)p * NB + b0 + n) * G3 + mt * 16 + q * 4;
        *(float4*)o = make_float4(acc[0], acc[1], acc[2], acc[3]);
    }
}

// ---------------- K4 v3: MFMA recurrence ----------------
__global__ __launch_bounds__(512, 2) void k_rnn3(const int* __restrict__ seq,
                                                 const int* __restrict__ lens,
                                                 const float* __restrict__ g,
                                                 const short* __restrict__ whA_hi,
                                                 const short* __restrict__ whA_lo,
                                                 const float* __restrict__ gx,
                                                 float* __restrict__ hlast) {
    int bid = blockIdx.x;
    int p  = bid / 16;
    int b0 = (bid % 16) * 16;
    int tid = threadIdx.x;
    int lane = tid & 63;
    int w = tid >> 6;
    int n = lane & 15;
    int q = lane >> 4;
    int d0 = w * 16 + q * 4;

    __shared__ __align__(16) unsigned short hH[2 * 2048];
    __shared__ __align__(16) unsigned short hL[2 * 2048];
    __shared__ float conc_s[SEQ * 16];

    for (int u = tid; u < 2048; u += 512) { hH[u] = 0; hL[u] = 0; }

    for (int e = tid; e < SEQ * 16; e += 512) {
        int t = e >> 4, b = e & 15;
        int ix = seq[t * NB + b0 + b];
        float cc = g[(size_t)ix * 3 + p];
        conc_s[e] = (cc >= EPS_C) ? cc : 0.f;
    }

    s16x8 whH[3][4], whL[3][4];
    int mts0 = w, mts1 = 8 + w, mts2 = 16 + w;
#pragma unroll
    for (int ks = 0; ks < 4; ++ks) {
        size_t o0 = ((((size_t)p * 24 + mts0) * 4 + ks) * 64 + lane) * 8;
        size_t o1 = ((((size_t)p * 24 + mts1) * 4 + ks) * 64 + lane) * 8;
        size_t o2 = ((((size_t)p * 24 + mts2) * 4 + ks) * 64 + lane) * 8;
        whH[0][ks] = *(const s16x8*)(whA_hi + o0);
        whH[1][ks] = *(const s16x8*)(whA_hi + o1);
        whH[2][ks] = *(const s16x8*)(whA_hi + o2);
        whL[0][ks] = *(const s16x8*)(whA_lo + o0);
        whL[1][ks] = *(const s16x8*)(whA_lo + o1);
        whL[2][ks] = *(const s16x8*)(whA_lo + o2);
    }

    int len_n = lens[b0 + n];
    float h0 = 0.f, h1 = 0.f, h2 = 0.f, h3 = 0.f;

    int wks = d0 >> 5;
    int km  = d0 & 31;
    int rl  = (km >> 3) * 16 + n;
    int jj0 = km & 7;
    int widx = wks * 512 + rl * 8 + jj0;

    const float* gxbase = gx + ((size_t)p * NB + (b0 + n)) * G3 + d0;
    const size_t tstride = (size_t)3 * NB * G3;

    f32x4 pgr = *(const f32x4*)(gxbase);
    f32x4 pgi = *(const f32x4*)(gxbase + DIM);
    f32x4 pgn = *(const f32x4*)(gxbase + 2 * DIM);

    __syncthreads();

    int cur = 0;
    for (int t = 0; t < SEQ; ++t) {
        f32x4 grv = pgr, giv = pgi, gnv = pgn;
        int tn = (t + 1 < SEQ) ? (t + 1) : t;
        const float* gp = gxbase + (size_t)tn * tstride;
        pgr = *(const f32x4*)(gp);
        pgi = *(const f32x4*)(gp + DIM);
        pgn = *(const f32x4*)(gp + 2 * DIM);

        float cc = conc_s[t * 16 + n];

        f32x4 acc0 = {0.f,0.f,0.f,0.f}, acc1 = {0.f,0.f,0.f,0.f}, acc2 = {0.f,0.f,0.f,0.f};
        const s16x8* bhp = (const s16x8*)hH + cur * 256 + lane;
        const s16x8* blp = (const s16x8*)hL + cur * 256 + lane;
#pragma unroll
        for (int ks = 0; ks < 4; ++ks) {
            s16x8 bh = bhp[ks * 64];
            s16x8 bl = blp[ks * 64];
            acc0 = __builtin_amdgcn_mfma_f32_16x16x32_bf16(whH[0][ks], bl, acc0, 0, 0, 0);
            acc1 = __builtin_amdgcn_mfma_f32_16x16x32_bf16(whH[1][ks], bl, acc1, 0, 0, 0);
            acc2 = __builtin_amdgcn_mfma_f32_16x16x32_bf16(whH[2][ks], bl, acc2, 0, 0, 0);
            acc0 = __builtin_amdgcn_mfma_f32_16x16x32_bf16(whL[0][ks], bh, acc0, 0, 0, 0);
            acc1 = __builtin_amdgcn_mfma_f32_16x16x32_bf16(whL[1][ks], bh, acc1, 0, 0, 0);
            acc2 = __builtin_amdgcn_mfma_f32_16x16x32_bf16(whL[2][ks], bh, acc2, 0, 0, 0);
            acc0 = __builtin_amdgcn_mfma_f32_16x16x32_bf16(whH[0][ks], bh, acc0, 0, 0, 0);
            acc1 = __builtin_amdgcn_mfma_f32_16x16x32_bf16(whH[1][ks], bh, acc1, 0, 0, 0);
            acc2 = __builtin_amdgcn_mfma_f32_16x16x32_bf16(whH[2][ks], bh, acc2, 0, 0, 0);
        }

        float ar[4], ai[4], an[4], gr4[4], gi4[4], gn4[4];
        *(f32x4*)ar = acc0; *(f32x4*)ai = acc1; *(f32x4*)an = acc2;
        *(f32x4*)gr4 = grv; *(f32x4*)gi4 = giv; *(f32x4*)gn4 = gnv;
        float hh[4] = {h0, h1, h2, h3};
        float hnew[4];
#pragma unroll
        for (int r = 0; r < 4; ++r) {
            float rr = sigmoidf_fast(gr4[r] + ar[r]);
            float ig = sigmoidf_fast(gi4[r] + ai[r]);
            float ng = tanhf_fast(gn4[r] + rr * an[r]);
            float m2 = cc * ig;
            hnew[r] = hh[r] + m2 * (ng - hh[r]);
        }
        h0 = hnew[0]; h1 = hnew[1]; h2 = hnew[2]; h3 = hnew[3];

        if (t == len_n - 1) {
            float* hp = hlast + (size_t)(b0 + n) * G3 + p * DIM + d0;
            *(float4*)hp = make_float4(h0, h1, h2, h3);
        }

        unsigned short sh[4], sl[4];
#pragma unroll
        for (int r = 0; r < 4; ++r) {
            sh[r] = f2bf(hnew[r]);
            sl[r] = f2bf(hnew[r] - bf2f(sh[r]));
        }
        int wb = (cur ^ 1) * 2048 + widx;
        *(uint2*)(hH + wb) = make_uint2((unsigned)sh[0] | ((unsigned)sh[1] << 16),
                                        (unsigned)sh[2] | ((unsigned)sh[3] << 16));
        *(uint2*)(hL + wb) = make_uint2((unsigned)sl[0] | ((unsigned)sl[1] << 16),
                                        (unsigned)sl[2] | ((unsigned)sl[3] << 16));
        __syncthreads();
        cur ^= 1;
    }
}

// ---------------- K4 fallback (no gx buffer) ----------------
__global__ __launch_bounds__(384) void k_rnn(const int* __restrict__ seq,
                                             const int* __restrict__ lens,
                                             const float* __restrict__ emb,
                                             const float* __restrict__ g,
                                             const float* __restrict__ wxT,
                                             const float* __restrict__ whT,
                                             float* __restrict__ hlast) {
    int bid = blockIdx.x;
    int b0 = (bid & 63) * 4;
    int p = bid >> 6;
    __shared__ __align__(16) float h_l[DIM * 4];
    __shared__ __align__(16) float x_l[DIM * 4];
    __shared__ __align__(16) float sx_l[G3 * 4];
    __shared__ __align__(16) float sh_l[G3 * 4];
    __shared__ float conc_l[4];
    __shared__ int idx_l[4];
    __shared__ int len_l[4];
    int tid = threadIdx.x;
    if (tid < 4) len_l[tid] = lens[b0 + tid];
    for (int u = tid; u < DIM * 4; u += 384) h_l[u] = 0.f;
    __syncthreads();
    const float* wh = whT + (size_t)p * (DIM * G3);
    const float* wx = wxT + (size_t)p * (DIM * G3);
    for (int t = 0; t < SEQ; ++t) {
        if (tid < 4) {
            int ix = seq[t * NB + b0 + tid];
            idx_l[tid] = ix;
            conc_l[tid] = g[(size_t)ix * 3 + p];
        }
        __syncthreads();
        for (int u = tid; u < DIM * 4; u += 384) {
            int bc = u >> 7, k = u & 127;
            x_l[k * 4 + bc] = emb[(size_t)idx_l[bc] * DIM + k];
        }
        __syncthreads();
        int j = tid;
        float ax0 = 0.f, ax1 = 0.f, ax2 = 0.f, ax3 = 0.f;
#pragma unroll 4
        for (int k = 0; k < DIM; ++k) {
            float wv = wx[(size_t)k * G3 + j];
            float4 xv = *(const float4*)(x_l + k * 4);
            ax0 += wv * xv.x; ax1 += wv * xv.y; ax2 += wv * xv.z; ax3 += wv * xv.w;
        }
        float ah0 = 0.f, ah1 = 0.f, ah2 = 0.f, ah3 = 0.f;
#pragma unroll 4
        for (int k = 0; k < DIM; ++k) {
            float wv = wh[(size_t)k * G3 + j];
            float4 hv = *(const float4*)(h_l + k * 4);
            ah0 += wv * hv.x; ah1 += wv * hv.y; ah2 += wv * hv.z; ah3 += wv * hv.w;
        }
        *(float4*)(sx_l + j * 4) = make_float4(ax0, ax1, ax2, ax3);
        *(float4*)(sh_l + j * 4) = make_float4(ah0, ah1, ah2, ah3);
        __syncthreads();
        for (int u = tid; u < DIM * 4; u += 384) {
            int bc = u & 3, d = u >> 2;
            float sr = sx_l[d * 4 + bc] + sh_l[d * 4 + bc];
            float si = sx_l[(DIM + d) * 4 + bc] + sh_l[(DIM + d) * 4 + bc];
            float xn = sx_l[(2 * DIM + d) * 4 + bc];
            float hn = sh_l[(2 * DIM + d) * 4 + bc];
            float r  = sigmoidf_fast(sr);
            float ig = sigmoidf_fast(si);
            float ng = tanhf_fast(xn + r * hn);
            float h  = h_l[d * 4 + bc];
            float cc = conc_l[bc];
            float multi = (cc >= EPS_C ? cc : 0.f) * ig;
            float hnew = h + multi * (ng - h);
            h_l[d * 4 + bc] = hnew;
            if (t == len_l[bc] - 1)
                hlast[(size_t)(b0 + bc) * G3 + p * DIM + d] = hnew;
        }
        __syncthreads();
    }
}

// ---------------- K4.5: split hlast into bf16 hi/lo, packed in A-fragment order ----------------
__global__ __launch_bounds__(256) void k_prep_h(const float* __restrict__ hlast,
                                                short* __restrict__ hl_hi,
                                                short* __restrict__ hl_lo) {
    int e = blockIdx.x * 256 + threadIdx.x;       // 98304
    int b = e / G3;
    int k = e % G3;
    float x = hlast[e];
    unsigned short hi = f2bf(x);
    unsigned short lo = f2bf(x - bf2f(hi));
    int off = (k >> 5) * 8192 + b * 32 + ((k >> 3) & 3) * 8 + (k & 7);
    hl_hi[off] = (short)hi;
    hl_lo[off] = (short)lo;
}

// ---------------- K5: logits via bf16 MFMA hi/lo (3-term), out = sigmoid ----------------
__global__ __launch_bounds__(256) void k_logits_mfma(const float* __restrict__ emb,
                                                     const float* __restrict__ c,
                                                     const short* __restrict__ hl_hi,
                                                     const short* __restrict__ hl_lo,
                                                     float* __restrict__ out) {
    int i0 = blockIdx.x * 64;
    int tid = threadIdx.x;
    int w = tid >> 6;
    int lane = tid & 63;
    int n = lane & 15;
    int q = lane >> 4;

    __shared__ __align__(16) float embs[64 * 132];

    for (int u = tid; u < 64 * 32; u += 256) {
        int i = u >> 5;
        int s = u & 31;
        int gi = i0 + i;
        float4 v = make_float4(0.f, 0.f, 0.f, 0.f);
        if (gi < N_ITEMS) v = *(const float4*)(emb + (size_t)gi * DIM + s * 4);
        *(float4*)(embs + i * 132 + s * 4) = v;
    }

    float cv[4][3];
#pragma unroll
    for (int is = 0; is < 4; ++is) {
        int gi = i0 + is * 16 + n;
#pragma unroll
        for (int p = 0; p < 3; ++p)
            cv[is][p] = (gi < N_ITEMS) ? c[(size_t)gi * 3 + p] : 0.f;
    }
    __syncthreads();

    f32x4 acc[4][4];
#pragma unroll
    for (int bs = 0; bs < 4; ++bs)
#pragma unroll
        for (int is = 0; is < 4; ++is)
            acc[bs][is] = (f32x4){0.f, 0.f, 0.f, 0.f};

    for (int ks = 0; ks < 12; ++ks) {
        int p = ks >> 2;
        int d0 = (ks & 3) * 32;
        int abase = ks * 8192 + (w * 64 + n) * 32 + q * 8;
        s16x8 ah[4], al[4];
#pragma unroll
        for (int bs = 0; bs < 4; ++bs) {
            ah[bs] = *(const s16x8*)(hl_hi + abase + bs * 512);
            al[bs] = *(const s16x8*)(hl_lo + abase + bs * 512);
        }
#pragma unroll
        for (int is = 0; is < 4; ++is) {
            const float* src = embs + (is * 16 + n) * 132 + d0 + q * 8;
            float x[8];
            *(float4*)(x)     = *(const float4*)(src);
            *(float4*)(x + 4) = *(const float4*)(src + 4);
            float sc = cv[is][p];
            s16x8 bhv, blv;
#pragma unroll
            for (int j = 0; j < 8; ++j) {
                float v = x[j] * sc;
                unsigned short h = f2bf(v);
                bhv[j] = (short)h;
                blv[j] = (short)f2bf(v - bf2f(h));
            }
#pragma unroll
            for (int bs = 0; bs < 4; ++bs) {
                acc[bs][is] = __builtin_amdgcn_mfma_f32_16x16x32_bf16(ah[bs], blv, acc[bs][is], 0, 0, 0);
                acc[bs][is] = __builtin_amdgcn_mfma_f32_16x16x32_bf16(al[bs], bhv, acc[bs][is], 0, 0, 0);
                acc[bs][is] = __builtin_amdgcn_mfma_f32_16x16x32_bf16(ah[bs], bhv, acc[bs][is], 0, 0, 0);
            }
        }
    }

#pragma unroll
    for (int is = 0; is < 4; ++is) {
        int gi = i0 + is * 16 + n;
        if (gi >= N_ITEMS) continue;
#pragma unroll
        for (int bs = 0; bs < 4; ++bs) {
            int brow = w * 64 + bs * 16 + q * 4;
#pragma unroll
            for (int r = 0; r < 4; ++r)
                out[(size_t)(brow + r) * N_ITEMS + gi] = sigmoidf_fast(acc[bs][is][r]);
        }
    }
}

extern "C" void kernel_launch(void* const* d_in, const int* in_sizes, int n_in,
                              void* d_out, int out_size, void* d_ws, size_t ws_size,
                              hipStream_t stream) {
    const int*   seq  = (const int*)d_in[0];
    const int*   lens = (const int*)d_in[1];
    const float* emb  = (const float*)d_in[2];
    const float* pt   = (const float*)d_in[3];
    const float* x2h  = (const float*)d_in[4];
    const float* h2h  = (const float*)d_in[5];
    float* out = (float*)d_out;
    float* ws  = (float*)d_ws;

    float* g     = ws + OFF_G;
    float* c     = ws + OFF_C;
    float* wxT   = ws + OFF_WXT;
    float* whT   = ws + OFF_WHT;
    float* hlast = ws + OFF_HLAST;
    float* gxbuf = ws + OFF_GX;
    short* wxA_hi = (short*)(ws + OFF_WXT);
    short* wxA_lo = wxA_hi + 147456;
    short* whA_hi = (short*)(ws + OFF_WHT);
    short* whA_lo = whA_hi + 147456;
    short* hl_hi = (short*)(ws + OFF_GX);       // aliases gx (dead after k_rnn3)
    short* hl_lo = hl_hi + 98304;

    int useGx = (ws_size >= (size_t)WS_FLOATS_PATHA * 4) ? 1 : 0;

    k_gc<<<3126, 256, 0, stream>>>(emb, pt, g, c);
    if (useGx) {
        k_prep_wA<<<144, 256, 0, stream>>>(x2h, h2h, wxA_hi, wxA_lo, whA_hi, whA_lo);
        k_gx_mfma<<<1600, 512, 0, stream>>>(seq, emb, wxA_hi, wxA_lo, gxbuf);
        k_rnn3<<<48, 512, 0, stream>>>(seq, lens, g, whA_hi, whA_lo, gxbuf, hlast);
    } else {
        k_prep_w<<<576, 256, 0, stream>>>(x2h, h2h, wxT, whT);
        k_rnn<<<192, 384, 0, stream>>>(seq, lens, emb, g, wxT, whT, hlast);
    }
    k_prep_h<<<384, 256, 0, stream>>>(hlast, hl_hi, hl_lo);
    k_logits_mfma<<<1563, 256, 0, stream>>>(emb, c, hl_hi, hl_lo, out);
}